// Round 12
// baseline (1509.179 us; speedup 1.0000x reference)
//
#include <hip/hip_runtime.h>

namespace {

constexpr int kB = 32;
constexpr int kT = 64;
constexpr int kH = 1024;
constexpr int kE = 1024;
constexpr int kV = 16000;
constexpr int kG = 4096;  // 4*H

typedef __attribute__((ext_vector_type(8))) short short8v;
typedef __attribute__((ext_vector_type(4))) float f32x4;

__device__ __forceinline__ float sigmoid_f(float x) {
  return 1.0f / (1.0f + __expf(-x));
}
__device__ __forceinline__ unsigned short f2bf(float x) {
  unsigned int u = __builtin_bit_cast(unsigned int, x);
  u = (u + 0x7FFFu + ((u >> 16) & 1u)) >> 16;
  return (unsigned short)u;
}
__device__ __forceinline__ float bf2f(unsigned short h) {
  return __builtin_bit_cast(float, (unsigned int)h << 16);
}

// ---------------- t=0 logits slice ----------------
__global__ void zero_t0_kernel(float* __restrict__ out) {
  int idx = blockIdx.x * blockDim.x + threadIdx.x;
  if (idx >= kB * kV) return;
  int b = idx / kV, v = idx % kV;
  __builtin_nontemporal_store(0.0f, &out[(size_t)b * kT * kV + v]);
}

// JAX outer-index semantics: out[b, 0, output_ids[j, 0]] = 1 for ALL (b, j)
__global__ void ones_t0_kernel(const int* __restrict__ output_ids,
                               float* __restrict__ out) {
  int b = threadIdx.x >> 5;
  int j = threadIdx.x & 31;
  int id = output_ids[j * kT];
  out[(size_t)b * kT * kV + id] = 1.0f;
}

// ---- fused one-time weight conversion: 8 matrices, mode 0=cell, 1=frag.
struct ConvJobs {
  const float* src[8];
  unsigned short* dst[8];
  int mode[8];
};
__global__ __launch_bounds__(256)
void conv8(ConvJobs C) {
  const int mat = blockIdx.x >> 11;
  const int idx = (blockIdx.x & 2047) * 256 + threadIdx.x;  // 0..524287
  const float* __restrict__ src = C.src[mat];
  unsigned short* __restrict__ dst = C.dst[mat];
  const int l = idx & 63;
  int row, k;
  if (C.mode[mat] == 0) {  // cell order
    const int kstep = (idx >> 6) & 31;
    const int uq = (idx >> 11) & 1;
    const int ub = idx >> 12;
    const int n = l & 15;
    row = (n >> 2) * kH + ub * 8 + uq * 4 + (n & 3);
    k = kstep * 32 + ((l >> 4) << 3);
  } else {  // frag order (16-row tiles)
    const int s = (idx >> 6) & 31;
    const int rg = idx >> 11;
    row = rg * 16 + (l & 15);
    k = s * 32 + ((l >> 4) << 3);
  }
  const float4* p = reinterpret_cast<const float4*>(src + (size_t)row * kH + k);
  float4 v0 = p[0], v1 = p[1];
  short8v o;
  o[0] = (short)f2bf(v0.x); o[1] = (short)f2bf(v0.y);
  o[2] = (short)f2bf(v0.z); o[3] = (short)f2bf(v0.w);
  o[4] = (short)f2bf(v1.x); o[5] = (short)f2bf(v1.y);
  o[6] = (short)f2bf(v1.z); o[7] = (short)f2bf(v1.w);
  *reinterpret_cast<short8v*>(dst + (size_t)idx * 8) = o;
}

// ---- convert fp32 row-major (R,1024) -> bf16 MFMA B-frag order (Wout).
__global__ __launch_bounds__(256)
void convert_frag(const float* __restrict__ src, unsigned short* __restrict__ dst,
                  int nchunks) {
  const int idx = blockIdx.x * 256 + threadIdx.x;
  if (idx >= nchunks) return;
  const int lane = idx & 63;
  const int s = (idx >> 6) & 31;
  const int rg = idx >> 11;
  const int row = rg * 16 + (lane & 15);
  const int k = s * 32 + ((lane >> 4) << 3);
  const float4* p = reinterpret_cast<const float4*>(src + (size_t)row * kH + k);
  float4 v0 = p[0], v1 = p[1];
  short8v o;
  o[0] = (short)f2bf(v0.x); o[1] = (short)f2bf(v0.y);
  o[2] = (short)f2bf(v0.z); o[3] = (short)f2bf(v0.w);
  o[4] = (short)f2bf(v1.x); o[5] = (short)f2bf(v1.y);
  o[6] = (short)f2bf(v1.z); o[7] = (short)f2bf(v1.w);
  *reinterpret_cast<short8v*>(dst + (size_t)idx * 8) = o;
}

// ---- combined L1 bias into cell order: dst[(u>>2)*16 + g*4 + (u&3)]
__global__ void bias_cell(const float* __restrict__ bih,
                          const float* __restrict__ bhh, float* __restrict__ dst) {
  const int i = blockIdx.x * 256 + threadIdx.x;
  if (i >= kG) return;
  const int g = i >> 10, u = i & 1023;
  dst[(u >> 2) * 16 + g * 4 + (u & 3)] = bih[i] + bhh[i];
}

// ---- gather embedding rows into A-frag bf16 layout.
__global__ __launch_bounds__(256)
void gather_frag(const float* __restrict__ emb, const int* __restrict__ ids,
                 unsigned short* __restrict__ dst, int ntiles) {
  const int idx = blockIdx.x * 256 + threadIdx.x;
  const int lane = idx & 63;
  const int s = (idx >> 6) & 31;
  const int tile = idx >> 11;
  if (tile >= ntiles) return;
  const int m = tile * 16 + (lane & 15);
  const int t = m >> 5, b = m & 31;
  const int id = ids[b * kT + t];
  const int k = s * 32 + ((lane >> 4) << 3);
  const float4* p = reinterpret_cast<const float4*>(emb + (size_t)id * kE + k);
  float4 v0 = p[0], v1 = p[1];
  short8v o;
  o[0] = (short)f2bf(v0.x); o[1] = (short)f2bf(v0.y);
  o[2] = (short)f2bf(v0.z); o[3] = (short)f2bf(v0.w);
  o[4] = (short)f2bf(v1.x); o[5] = (short)f2bf(v1.y);
  o[6] = (short)f2bf(v1.z); o[7] = (short)f2bf(v1.w);
  *reinterpret_cast<short8v*>(dst + (size_t)idx * 8) = o;
}

// ---- proj MFMA: writes xproj in CELL-ORDER: [t][q][m 32][16 = g*4+uu] bf16.
__global__ __launch_bounds__(256)
void proj_mfma(const unsigned short* __restrict__ Af,
               const unsigned short* __restrict__ Bf,
               const float* __restrict__ b0, const float* __restrict__ b1,
               unsigned short* __restrict__ dst, int nmt) {
  const int w = threadIdx.x >> 6, lane = threadIdx.x & 63;
  const int mg = blockIdx.x, ng = blockIdx.y;
  f32x4 acc[4][2] = {};
  const unsigned short* Ab[4];
  const unsigned short* Bb[2];
#pragma unroll
  for (int i = 0; i < 4; ++i) {
    int tile = mg * 4 + i;
    if (tile > nmt - 1) tile = nmt - 1;
    Ab[i] = Af + (size_t)tile * 16384 + lane * 8;
  }
#pragma unroll
  for (int j = 0; j < 2; ++j) {
    const int nt = ng * 8 + w * 2 + j;
    Bb[j] = Bf + (size_t)nt * 16384 + lane * 8;
  }
#pragma unroll 2
  for (int s = 0; s < 32; ++s) {
    short8v a[4], b[2];
#pragma unroll
    for (int i = 0; i < 4; ++i) a[i] = *reinterpret_cast<const short8v*>(Ab[i] + s * 512);
#pragma unroll
    for (int j = 0; j < 2; ++j) b[j] = *reinterpret_cast<const short8v*>(Bb[j] + s * 512);
#pragma unroll
    for (int i = 0; i < 4; ++i)
#pragma unroll
      for (int j = 0; j < 2; ++j)
        acc[i][j] = __builtin_amdgcn_mfma_f32_16x16x32_bf16(a[i], b[j], acc[i][j], 0, 0, 0);
  }
#pragma unroll
  for (int i = 0; i < 4; ++i) {
    const int tile = mg * 4 + i;
    if (tile >= nmt) continue;
    const int mbase = tile * 16 + ((lane >> 4) << 2);
#pragma unroll
    for (int j = 0; j < 2; ++j) {
      const int n = (ng * 8 + w * 2 + j) * 16 + (lane & 15);
      const float bj = b0[n] + b1[n];
      const int g = n >> 10;
      const int u = n & 1023;
      const int q = u >> 2;
      const int uu = u & 3;
#pragma unroll
      for (int r = 0; r < 4; ++r) {
        const int m2 = mbase + r;
        const int t = m2 >> 5, mb = m2 & 31;
        dst[(size_t)t * kB * kG + (size_t)(q * 32 + mb) * 16 + g * 4 + uu] =
            f2bf(acc[i][j][r] + bj);
      }
    }
  }
}

// ---- output GEMM MFMA: XCD-swizzled 1-D grid; 4x4 tiles/wave; ONE-PASS
// 16-row LDS transpose epilogue (16.6 KB) for ~5 blocks/CU occupancy.
__global__ __launch_bounds__(256, 5)
void out_gemm_mfma(const unsigned short* __restrict__ Af,
                   const unsigned short* __restrict__ Bf,
                   const float* __restrict__ bias, float* __restrict__ out) {
  const int w = threadIdx.x >> 6, lane = threadIdx.x & 63;
  const int bid = blockIdx.x;
  const int swz = (bid & 7) * 252 + (bid >> 3);
  const int mg = swz & 31, ng = swz >> 5;
  __shared__ float LsF[16 * 260];
  f32x4 acc[4][4] = {};
  const unsigned short* Ab[4];
  const unsigned short* Bb[4];
#pragma unroll
  for (int i = 0; i < 4; ++i) {
    int tile = mg * 4 + i;
    if (tile > 125) tile = 125;
    Ab[i] = Af + (size_t)tile * 16384 + lane * 8;
  }
#pragma unroll
  for (int j = 0; j < 4; ++j) {
    int nt = ng * 16 + w * 4 + j;
    if (nt > 999) nt = 999;
    Bb[j] = Bf + (size_t)nt * 16384 + lane * 8;
  }
#pragma unroll 2
  for (int s = 0; s < 32; ++s) {
    short8v a[4], b[4];
#pragma unroll
    for (int i = 0; i < 4; ++i) a[i] = *reinterpret_cast<const short8v*>(Ab[i] + s * 512);
#pragma unroll
    for (int j = 0; j < 4; ++j) b[j] = *reinterpret_cast<const short8v*>(Bb[j] + s * 512);
#pragma unroll
    for (int i = 0; i < 4; ++i)
#pragma unroll
      for (int j = 0; j < 4; ++j)
        acc[i][j] = __builtin_amdgcn_mfma_f32_16x16x32_bf16(a[i], b[j], acc[i][j], 0, 0, 0);
  }
  const int nglob = ng * 256 + lane * 4;
  f32x4 b4 = {0.f, 0.f, 0.f, 0.f};
  if (nglob < kV) b4 = *reinterpret_cast<const f32x4*>(&bias[nglob]);
#pragma unroll
  for (int i = 0; i < 4; ++i) {
    if (i) __syncthreads();
    const int r2b = (lane >> 4) << 2;
#pragma unroll
    for (int j = 0; j < 4; ++j) {
      const int nloc = (w * 4 + j) * 16 + (lane & 15);
#pragma unroll
      for (int r = 0; r < 4; ++r) LsF[(r2b + r) * 260 + nloc] = acc[i][j][r];
    }
    __syncthreads();
    if (nglob < kV) {
#pragma unroll
      for (int it = 0; it < 4; ++it) {
        const int r2l = w * 4 + it;
        const int m = mg * 64 + i * 16 + r2l;
        if (m < 2016) {
          f32x4 v = *reinterpret_cast<const f32x4*>(&LsF[r2l * 260 + lane * 4]);
          v += b4;
          const int sd = m >> 5, bb = m & 31;
          f32x4* dst = reinterpret_cast<f32x4*>(
              &out[(size_t)bb * kT * kV + (size_t)(sd + 1) * kV + nglob]);
          __builtin_nontemporal_store(v, dst);
        }
      }
    }
  }
}

// ---- persistent recurrence, fence-free, LOW-CONTENTION barrier.
// Arrival: one atomic_fetch_add per block on ctr[p] (stride-16 ints).
// Poll: ONE lane per block loads ONE counter (256 loads/round vs 65536
// before — the R11 barrier was TCC-contention-bound on the flag lines).
struct RecurArgs {
  const unsigned short* wih1[2];  // enc, dec (cell layout)
  const unsigned short* whh1[2];
  const unsigned short* whh0[2];
  const unsigned short* xproj[2];  // cell-order bases
  const float* bsum1[2];           // cell-order combined L1 bias
  unsigned short* h0seq;  // 128 slots x 32768 elems (slot p = h0 state t=p-1)
  unsigned short* h1seq;  // 128 slots (slot p = h1 state t=p-1)
  int* ctr;               // 128 counters, stride 16 ints, zeroed per launch
};

#define LOADW(dst, src)                                                      \
  {                                                                          \
    _Pragma("unroll") for (int s_ = 0; s_ < 4; ++s_) dst[s_] =               \
        *reinterpret_cast<const short8v*>((src) + wbase + (size_t)s_ * 512); \
  }

__global__ __launch_bounds__(512, 1)
void lstm_persist(RecurArgs A) {
  const int q = blockIdx.x;
  const int tid = threadIdx.x;
  const int wave = tid >> 6, lane = tid & 63;
  const int ksb = wave * 4;
  // Ls[prod][wave][mt][lane][r]; prod: 0=ih1, 1=hh1, 2=hh0
  __shared__ alignas(16) float Ls[3][8][2][64][4];  // 48 KB

  const size_t wbase = ((size_t)(q * 32 + ksb) * 64 + lane) * 8;
  short8v wI[4], wJ[4], wH[4];
  LOADW(wI, A.wih1[0]);
  LOADW(wJ, A.whh1[0]);
  LOADW(wH, A.whh0[0]);

  // epilogue-thread persistent state
  const int m = (tid < 128) ? (tid >> 2) : 0;  // batch row
  const int ul = tid & 3;
  const int u = q * 4 + ul;
  float cold0 = 0.f, cold1 = 0.f;
  float bs[4];
  if (tid < 128) {
#pragma unroll
    for (int g = 0; g < 4; ++g) bs[g] = A.bsum1[0][q * 16 + g * 4 + ul];
  }
  const int mt = m >> 4, r = m & 3;
  const int lm = (m & 12) << 2;
  const int ksu = u >> 5;
  const int lane3 = (m & 15) | (((u >> 3) & 3) << 4);
  const int e = u & 7;
  const size_t fidx = (size_t)((mt * 32 + ksu) * 64 + lane3) * 8 + e;

  for (int p = 0; p < 128; ++p) {
    if (p == 64) LOADW(wH, A.whh0[1]);
    if (p == 65) {
      LOADW(wI, A.wih1[1]);
      LOADW(wJ, A.whh1[1]);
      if (tid < 128) {
#pragma unroll
        for (int g = 0; g < 4; ++g) bs[g] = A.bsum1[1][q * 16 + g * 4 + ul];
      }
    }
    // xproj prefetch for L0(p) (covered by MFMA phase latency)
    float xp[4] = {};
    if (tid < 128 && p <= 126) {
      const int e0 = (p < kT) ? 0 : 1;
      const unsigned short* xprojc =
          A.xproj[e0] + (size_t)(e0 ? (p - kT) : p) * kB * kG;
#pragma unroll
      for (int g = 0; g < 4; ++g)
        xp[g] = bf2f(xprojc[(q * 32 + m) * 16 + g * 4 + ul]);
    }

    const unsigned short* A0 = A.h0seq + (size_t)p * 32768;
    const unsigned short* A1 = A.h1seq + (size_t)(p > 0 ? p - 1 : 0) * 32768;

    f32x4 aI0 = {0.f, 0.f, 0.f, 0.f}, aI1 = {0.f, 0.f, 0.f, 0.f};
    f32x4 aJ0 = {0.f, 0.f, 0.f, 0.f}, aJ1 = {0.f, 0.f, 0.f, 0.f};
    f32x4 aH0 = {0.f, 0.f, 0.f, 0.f}, aH1 = {0.f, 0.f, 0.f, 0.f};
#pragma unroll
    for (int s = 0; s < 4; ++s) {
      const int ks = ksb + s;
      const short8v a00 =
          *reinterpret_cast<const short8v*>(A0 + (size_t)(ks * 64 + lane) * 8);
      const short8v a01 =
          *reinterpret_cast<const short8v*>(A0 + (size_t)((32 + ks) * 64 + lane) * 8);
      const short8v a10 =
          *reinterpret_cast<const short8v*>(A1 + (size_t)(ks * 64 + lane) * 8);
      const short8v a11 =
          *reinterpret_cast<const short8v*>(A1 + (size_t)((32 + ks) * 64 + lane) * 8);
      aI0 = __builtin_amdgcn_mfma_f32_16x16x32_bf16(a00, wI[s], aI0, 0, 0, 0);
      aI1 = __builtin_amdgcn_mfma_f32_16x16x32_bf16(a01, wI[s], aI1, 0, 0, 0);
      aJ0 = __builtin_amdgcn_mfma_f32_16x16x32_bf16(a10, wJ[s], aJ0, 0, 0, 0);
      aJ1 = __builtin_amdgcn_mfma_f32_16x16x32_bf16(a11, wJ[s], aJ1, 0, 0, 0);
      aH0 = __builtin_amdgcn_mfma_f32_16x16x32_bf16(a00, wH[s], aH0, 0, 0, 0);
      aH1 = __builtin_amdgcn_mfma_f32_16x16x32_bf16(a01, wH[s], aH1, 0, 0, 0);
    }
    *reinterpret_cast<f32x4*>(&Ls[0][wave][0][lane][0]) = aI0;
    *reinterpret_cast<f32x4*>(&Ls[0][wave][1][lane][0]) = aI1;
    *reinterpret_cast<f32x4*>(&Ls[1][wave][0][lane][0]) = aJ0;
    *reinterpret_cast<f32x4*>(&Ls[1][wave][1][lane][0]) = aJ1;
    *reinterpret_cast<f32x4*>(&Ls[2][wave][0][lane][0]) = aH0;
    *reinterpret_cast<f32x4*>(&Ls[2][wave][1][lane][0]) = aH1;
    __syncthreads();

    if (tid < 128) {
      if (p <= 126) {  // L0(p)
        float g0[4];
#pragma unroll
        for (int g = 0; g < 4; ++g) {
          const int ln = (g * 4 + ul) | lm;
          float v = 0.f;
#pragma unroll
          for (int ww = 0; ww < 8; ++ww) v += Ls[2][ww][mt][ln][r];
          g0[g] = v + xp[g];
        }
        const float cnew = sigmoid_f(g0[1]) * cold0 + sigmoid_f(g0[0]) * tanhf(g0[2]);
        const float hnew = sigmoid_f(g0[3]) * tanhf(cnew);
        cold0 = cnew;
        const unsigned int hb = f2bf(hnew);
        const unsigned int other = __shfl_xor((int)hb, 1);
        if ((ul & 1) == 0) {
          unsigned int word = (hb & 0xffffu) | (other << 16);
          unsigned int* dst = reinterpret_cast<unsigned int*>(
              A.h0seq + (size_t)(p + 1) * 32768 + fidx);
          __hip_atomic_store(dst, word, __ATOMIC_RELAXED,
                             __HIP_MEMORY_SCOPE_AGENT);
        }
      }
      if (p >= 1) {  // L1(p-1)
        float g1[4];
#pragma unroll
        for (int g = 0; g < 4; ++g) {
          const int ln = (g * 4 + ul) | lm;
          float v = 0.f;
#pragma unroll
          for (int ww = 0; ww < 8; ++ww)
            v += Ls[0][ww][mt][ln][r] + Ls[1][ww][mt][ln][r];
          g1[g] = v + bs[g];
        }
        const float cnew = sigmoid_f(g1[1]) * cold1 + sigmoid_f(g1[0]) * tanhf(g1[2]);
        const float hnew = sigmoid_f(g1[3]) * tanhf(cnew);
        cold1 = cnew;
        const unsigned int hb = f2bf(hnew);
        const unsigned int other = __shfl_xor((int)hb, 1);
        if ((ul & 1) == 0) {
          unsigned int word = (hb & 0xffffu) | (other << 16);
          unsigned int* dst = reinterpret_cast<unsigned int*>(
              A.h1seq + (size_t)p * 32768 + fidx);
          __hip_atomic_store(dst, word, __ATOMIC_RELAXED,
                             __HIP_MEMORY_SCOPE_AGENT);
        }
      }
    }

    // ---- step barrier (fence-free, low-contention) ----
    asm volatile("s_waitcnt vmcnt(0)" ::: "memory");  // h stores at L3
    __syncthreads();                                  // all waves drained
    if (tid == 0) {
      __hip_atomic_fetch_add(&A.ctr[p * 16], 1, __ATOMIC_RELAXED,
                             __HIP_MEMORY_SCOPE_AGENT);
      for (int guard = 0; guard < (1 << 15); ++guard) {
        const int v = __hip_atomic_load(&A.ctr[p * 16], __ATOMIC_RELAXED,
                                        __HIP_MEMORY_SCOPE_AGENT);
        if (v >= 256) break;
        __builtin_amdgcn_s_sleep(2);
      }
    }
    __syncthreads();  // release whole block
  }
}

}  // namespace

extern "C" void kernel_launch(void* const* d_in, const int* in_sizes, int n_in,
                              void* d_out, int out_size, void* d_ws, size_t ws_size,
                              hipStream_t stream) {
  const int* input_ids = (const int*)d_in[0];
  const int* output_ids = (const int*)d_in[1];
  const float* enc_emb = (const float*)d_in[2];
  const float* enc_Wih = (const float*)d_in[3];
  const float* enc_Whh = (const float*)d_in[4];
  const float* enc_bih = (const float*)d_in[5];
  const float* enc_bhh = (const float*)d_in[6];
  const float* dec_emb = (const float*)d_in[7];
  const float* dec_Wih = (const float*)d_in[8];
  const float* dec_Whh = (const float*)d_in[9];
  const float* dec_bih = (const float*)d_in[10];
  const float* dec_bhh = (const float*)d_in[11];
  const float* Wout = (const float*)d_in[12];
  const float* bout = (const float*)d_in[13];
  float* out = (float*)d_out;
  char* ws = (char*)d_ws;

  const size_t WL = (size_t)kG * kH;  // per-layer weight stride (elems)

  // ---- workspace layout (bytes) ----
  size_t off = 0;
  unsigned short* wout_frag = (unsigned short*)(ws + 0);
  unsigned short* xproj_enc = (unsigned short*)(ws + off); off += (size_t)kT * kB * kG * 2;
  unsigned short* xin_enc = (unsigned short*)(ws + off);
  unsigned short* h0seq = xin_enc;  // alias (8.39 MB <= 12.58 MB region)
  off += (size_t)kT * kB * kH * 2;
  unsigned short* wih0_enc = (unsigned short*)(ws + off); off += WL * 2;
  unsigned short* wih0_dec = (unsigned short*)(ws + off); off += WL * 2;
  // persistent regions
  unsigned short* xproj_dec = (unsigned short*)(ws + off); off += (size_t)(kT - 1) * kB * kG * 2;
  unsigned short* xin_dec = (unsigned short*)(ws + off); off += (size_t)(kT - 1) * kB * kH * 2;
  unsigned short* h1seq = (unsigned short*)(ws + off); off += (size_t)128 * kB * kH * 2;
  unsigned short* wswz[6];
  for (int i = 0; i < 6; ++i) { wswz[i] = (unsigned short*)(ws + off); off += WL * 2; }
  float* bsum_enc = (float*)(ws + off); off += kG * 4;
  float* bsum_dec = (float*)(ws + off); off += kG * 4;
  int* ctr = (int*)(ws + off); off += 128 * 16 * 4;

  // one-time weight conversions (single fused launch)
  ConvJobs C;
  C.src[0] = enc_Whh;       C.dst[0] = wswz[0];    C.mode[0] = 0;
  C.src[1] = enc_Wih + WL;  C.dst[1] = wswz[1];    C.mode[1] = 0;
  C.src[2] = enc_Whh + WL;  C.dst[2] = wswz[2];    C.mode[2] = 0;
  C.src[3] = dec_Whh;       C.dst[3] = wswz[3];    C.mode[3] = 0;
  C.src[4] = dec_Wih + WL;  C.dst[4] = wswz[4];    C.mode[4] = 0;
  C.src[5] = dec_Whh + WL;  C.dst[5] = wswz[5];    C.mode[5] = 0;
  C.src[6] = enc_Wih;       C.dst[6] = wih0_enc;   C.mode[6] = 1;
  C.src[7] = dec_Wih;       C.dst[7] = wih0_dec;   C.mode[7] = 1;
  conv8<<<8 * 2048, 256, 0, stream>>>(C);
  bias_cell<<<16, 256, 0, stream>>>(enc_bih + kG, enc_bhh + kG, bsum_enc);
  bias_cell<<<16, 256, 0, stream>>>(dec_bih + kG, dec_bhh + kG, bsum_dec);

  // gather embeddings into A-frag layout
  gather_frag<<<128 * 8, 256, 0, stream>>>(enc_emb, input_ids, xin_enc, 128);
  gather_frag<<<126 * 8, 256, 0, stream>>>(dec_emb, output_ids, xin_dec, 126);

  // layer-0 input projections (bias fused, bf16 cell-order out)
  proj_mfma<<<dim3(32, 32), 256, 0, stream>>>(xin_enc, wih0_enc, enc_bih, enc_bhh,
                                              xproj_enc, 128);
  proj_mfma<<<dim3(32, 32), 256, 0, stream>>>(xin_dec, wih0_dec, dec_bih, dec_bhh,
                                              xproj_dec, 126);

  // zero h0seq slot 0, h1seq slot 0, counters (AFTER proj: h0seq aliases xin_enc)
  (void)hipMemsetAsync(h0seq, 0, (size_t)kB * kH * 2, stream);
  (void)hipMemsetAsync(h1seq, 0, (size_t)kB * kH * 2, stream);
  (void)hipMemsetAsync(ctr, 0, 128 * 16 * 4, stream);

  // ---- recurrence: ONE persistent fence-free kernel, 128 steps ----
  RecurArgs RA;
  RA.wih1[0] = wswz[1]; RA.wih1[1] = wswz[4];
  RA.whh1[0] = wswz[2]; RA.whh1[1] = wswz[5];
  RA.whh0[0] = wswz[0]; RA.whh0[1] = wswz[3];
  RA.xproj[0] = xproj_enc; RA.xproj[1] = xproj_dec;
  RA.bsum1[0] = bsum_enc; RA.bsum1[1] = bsum_dec;
  RA.h0seq = h0seq;
  RA.h1seq = h1seq;
  RA.ctr = ctr;
  lstm_persist<<<256, 512, 0, stream>>>(RA);

  // Wout frags (aliases region A — runs after the recurrence)
  convert_frag<<<8000, 256, 0, stream>>>(Wout, wout_frag, kV * (kH / 8));

  // logits[:, 0, :]
  zero_t0_kernel<<<(kB * kV + 255) / 256, 256, 0, stream>>>(out);
  ones_t0_kernel<<<1, kB * kB, 0, stream>>>(output_ids, out);

  // logits[:, 1:, :] — htop IS h1seq slots 65..127 (126 m-tiles, contiguous)
  out_gemm_mfma<<<2016, 256, 0, stream>>>(h1seq + (size_t)65 * kB * kH,
                                          wout_frag, bout, out);
}

// Round 13
// 1198.338 us; speedup vs baseline: 1.2594x; 1.2594x over previous
//
#include <hip/hip_runtime.h>

namespace {

constexpr int kB = 32;
constexpr int kT = 64;
constexpr int kH = 1024;
constexpr int kE = 1024;
constexpr int kV = 16000;
constexpr int kG = 4096;  // 4*H

typedef __attribute__((ext_vector_type(8))) short short8v;
typedef __attribute__((ext_vector_type(4))) float f32x4;

__device__ __forceinline__ float sigmoid_f(float x) {
  return 1.0f / (1.0f + __expf(-x));
}
__device__ __forceinline__ unsigned short f2bf(float x) {
  unsigned int u = __builtin_bit_cast(unsigned int, x);
  u = (u + 0x7FFFu + ((u >> 16) & 1u)) >> 16;
  return (unsigned short)u;
}
__device__ __forceinline__ float bf2f(unsigned short h) {
  return __builtin_bit_cast(float, (unsigned int)h << 16);
}

// ---------------- t=0 logits slice ----------------
__global__ void zero_t0_kernel(float* __restrict__ out) {
  int idx = blockIdx.x * blockDim.x + threadIdx.x;
  if (idx >= kB * kV) return;
  int b = idx / kV, v = idx % kV;
  __builtin_nontemporal_store(0.0f, &out[(size_t)b * kT * kV + v]);
}

// JAX outer-index semantics: out[b, 0, output_ids[j, 0]] = 1 for ALL (b, j)
__global__ void ones_t0_kernel(const int* __restrict__ output_ids,
                               float* __restrict__ out) {
  int b = threadIdx.x >> 5;
  int j = threadIdx.x & 31;
  int id = output_ids[j * kT];
  out[(size_t)b * kT * kV + id] = 1.0f;
}

// ---- fused one-time weight conversion: 8 matrices, mode 0=cell, 1=frag.
struct ConvJobs {
  const float* src[8];
  unsigned short* dst[8];
  int mode[8];
};
__global__ __launch_bounds__(256)
void conv8(ConvJobs C) {
  const int mat = blockIdx.x >> 11;
  const int idx = (blockIdx.x & 2047) * 256 + threadIdx.x;  // 0..524287
  const float* __restrict__ src = C.src[mat];
  unsigned short* __restrict__ dst = C.dst[mat];
  const int l = idx & 63;
  int row, k;
  if (C.mode[mat] == 0) {  // cell order
    const int kstep = (idx >> 6) & 31;
    const int uq = (idx >> 11) & 1;
    const int ub = idx >> 12;
    const int n = l & 15;
    row = (n >> 2) * kH + ub * 8 + uq * 4 + (n & 3);
    k = kstep * 32 + ((l >> 4) << 3);
  } else {  // frag order (16-row tiles)
    const int s = (idx >> 6) & 31;
    const int rg = idx >> 11;
    row = rg * 16 + (l & 15);
    k = s * 32 + ((l >> 4) << 3);
  }
  const float4* p = reinterpret_cast<const float4*>(src + (size_t)row * kH + k);
  float4 v0 = p[0], v1 = p[1];
  short8v o;
  o[0] = (short)f2bf(v0.x); o[1] = (short)f2bf(v0.y);
  o[2] = (short)f2bf(v0.z); o[3] = (short)f2bf(v0.w);
  o[4] = (short)f2bf(v1.x); o[5] = (short)f2bf(v1.y);
  o[6] = (short)f2bf(v1.z); o[7] = (short)f2bf(v1.w);
  *reinterpret_cast<short8v*>(dst + (size_t)idx * 8) = o;
}

// ---- convert fp32 row-major (R,1024) -> bf16 MFMA B-frag order (Wout).
__global__ __launch_bounds__(256)
void convert_frag(const float* __restrict__ src, unsigned short* __restrict__ dst,
                  int nchunks) {
  const int idx = blockIdx.x * 256 + threadIdx.x;
  if (idx >= nchunks) return;
  const int lane = idx & 63;
  const int s = (idx >> 6) & 31;
  const int rg = idx >> 11;
  const int row = rg * 16 + (lane & 15);
  const int k = s * 32 + ((lane >> 4) << 3);
  const float4* p = reinterpret_cast<const float4*>(src + (size_t)row * kH + k);
  float4 v0 = p[0], v1 = p[1];
  short8v o;
  o[0] = (short)f2bf(v0.x); o[1] = (short)f2bf(v0.y);
  o[2] = (short)f2bf(v0.z); o[3] = (short)f2bf(v0.w);
  o[4] = (short)f2bf(v1.x); o[5] = (short)f2bf(v1.y);
  o[6] = (short)f2bf(v1.z); o[7] = (short)f2bf(v1.w);
  *reinterpret_cast<short8v*>(dst + (size_t)idx * 8) = o;
}

// ---- combined L1 bias into cell order: dst[(u>>2)*16 + g*4 + (u&3)]
__global__ void bias_cell(const float* __restrict__ bih,
                          const float* __restrict__ bhh, float* __restrict__ dst) {
  const int i = blockIdx.x * 256 + threadIdx.x;
  if (i >= kG) return;
  const int g = i >> 10, u = i & 1023;
  dst[(u >> 2) * 16 + g * 4 + (u & 3)] = bih[i] + bhh[i];
}

// ---- gather embedding rows into A-frag bf16 layout.
__global__ __launch_bounds__(256)
void gather_frag(const float* __restrict__ emb, const int* __restrict__ ids,
                 unsigned short* __restrict__ dst, int ntiles) {
  const int idx = blockIdx.x * 256 + threadIdx.x;
  const int lane = idx & 63;
  const int s = (idx >> 6) & 31;
  const int tile = idx >> 11;
  if (tile >= ntiles) return;
  const int m = tile * 16 + (lane & 15);
  const int t = m >> 5, b = m & 31;
  const int id = ids[b * kT + t];
  const int k = s * 32 + ((lane >> 4) << 3);
  const float4* p = reinterpret_cast<const float4*>(emb + (size_t)id * kE + k);
  float4 v0 = p[0], v1 = p[1];
  short8v o;
  o[0] = (short)f2bf(v0.x); o[1] = (short)f2bf(v0.y);
  o[2] = (short)f2bf(v0.z); o[3] = (short)f2bf(v0.w);
  o[4] = (short)f2bf(v1.x); o[5] = (short)f2bf(v1.y);
  o[6] = (short)f2bf(v1.z); o[7] = (short)f2bf(v1.w);
  *reinterpret_cast<short8v*>(dst + (size_t)idx * 8) = o;
}

// ---- proj MFMA: writes xproj in CELL-ORDER: [t][q][m 32][16 = g*4+uu] bf16.
__global__ __launch_bounds__(256)
void proj_mfma(const unsigned short* __restrict__ Af,
               const unsigned short* __restrict__ Bf,
               const float* __restrict__ b0, const float* __restrict__ b1,
               unsigned short* __restrict__ dst, int nmt) {
  const int w = threadIdx.x >> 6, lane = threadIdx.x & 63;
  const int mg = blockIdx.x, ng = blockIdx.y;
  f32x4 acc[4][2] = {};
  const unsigned short* Ab[4];
  const unsigned short* Bb[2];
#pragma unroll
  for (int i = 0; i < 4; ++i) {
    int tile = mg * 4 + i;
    if (tile > nmt - 1) tile = nmt - 1;
    Ab[i] = Af + (size_t)tile * 16384 + lane * 8;
  }
#pragma unroll
  for (int j = 0; j < 2; ++j) {
    const int nt = ng * 8 + w * 2 + j;
    Bb[j] = Bf + (size_t)nt * 16384 + lane * 8;
  }
#pragma unroll 2
  for (int s = 0; s < 32; ++s) {
    short8v a[4], b[2];
#pragma unroll
    for (int i = 0; i < 4; ++i) a[i] = *reinterpret_cast<const short8v*>(Ab[i] + s * 512);
#pragma unroll
    for (int j = 0; j < 2; ++j) b[j] = *reinterpret_cast<const short8v*>(Bb[j] + s * 512);
#pragma unroll
    for (int i = 0; i < 4; ++i)
#pragma unroll
      for (int j = 0; j < 2; ++j)
        acc[i][j] = __builtin_amdgcn_mfma_f32_16x16x32_bf16(a[i], b[j], acc[i][j], 0, 0, 0);
  }
#pragma unroll
  for (int i = 0; i < 4; ++i) {
    const int tile = mg * 4 + i;
    if (tile >= nmt) continue;
    const int mbase = tile * 16 + ((lane >> 4) << 2);
#pragma unroll
    for (int j = 0; j < 2; ++j) {
      const int n = (ng * 8 + w * 2 + j) * 16 + (lane & 15);
      const float bj = b0[n] + b1[n];
      const int g = n >> 10;
      const int u = n & 1023;
      const int q = u >> 2;
      const int uu = u & 3;
#pragma unroll
      for (int r = 0; r < 4; ++r) {
        const int m2 = mbase + r;
        const int t = m2 >> 5, mb = m2 & 31;
        dst[(size_t)t * kB * kG + (size_t)(q * 32 + mb) * 16 + g * 4 + uu] =
            f2bf(acc[i][j][r] + bj);
      }
    }
  }
}

// ---- output GEMM MFMA (R10 known-good): XCD-swizzled 1-D grid; 4x4
// tiles/wave; two-pass 32-row LDS transpose epilogue -> f32x4 NT stores.
__global__ __launch_bounds__(256)
void out_gemm_mfma(const unsigned short* __restrict__ Af,
                   const unsigned short* __restrict__ Bf,
                   const float* __restrict__ bias, float* __restrict__ out) {
  const int w = threadIdx.x >> 6, lane = threadIdx.x & 63;
  const int bid = blockIdx.x;
  const int swz = (bid & 7) * 252 + (bid >> 3);
  const int mg = swz & 31, ng = swz >> 5;
  __shared__ float LsF[32 * 260];
  f32x4 acc[4][4] = {};
  const unsigned short* Ab[4];
  const unsigned short* Bb[4];
#pragma unroll
  for (int i = 0; i < 4; ++i) {
    int tile = mg * 4 + i;
    if (tile > 125) tile = 125;
    Ab[i] = Af + (size_t)tile * 16384 + lane * 8;
  }
#pragma unroll
  for (int j = 0; j < 4; ++j) {
    int nt = ng * 16 + w * 4 + j;
    if (nt > 999) nt = 999;
    Bb[j] = Bf + (size_t)nt * 16384 + lane * 8;
  }
#pragma unroll 2
  for (int s = 0; s < 32; ++s) {
    short8v a[4], b[4];
#pragma unroll
    for (int i = 0; i < 4; ++i) a[i] = *reinterpret_cast<const short8v*>(Ab[i] + s * 512);
#pragma unroll
    for (int j = 0; j < 4; ++j) b[j] = *reinterpret_cast<const short8v*>(Bb[j] + s * 512);
#pragma unroll
    for (int i = 0; i < 4; ++i)
#pragma unroll
      for (int j = 0; j < 4; ++j)
        acc[i][j] = __builtin_amdgcn_mfma_f32_16x16x32_bf16(a[i], b[j], acc[i][j], 0, 0, 0);
  }
  const int nglob = ng * 256 + lane * 4;
  f32x4 b4 = {0.f, 0.f, 0.f, 0.f};
  if (nglob < kV) b4 = *reinterpret_cast<const f32x4*>(&bias[nglob]);
#pragma unroll
  for (int ph = 0; ph < 2; ++ph) {
    if (ph) __syncthreads();
#pragma unroll
    for (int i2 = 0; i2 < 2; ++i2) {
      const int i = ph * 2 + i2;
      const int r2b = i2 * 16 + ((lane >> 4) << 2);
#pragma unroll
      for (int j = 0; j < 4; ++j) {
        const int nloc = (w * 4 + j) * 16 + (lane & 15);
#pragma unroll
        for (int r = 0; r < 4; ++r) LsF[(r2b + r) * 260 + nloc] = acc[i][j][r];
      }
    }
    __syncthreads();
    if (nglob < kV) {
#pragma unroll
      for (int it = 0; it < 8; ++it) {
        const int r2l = w * 8 + it;
        const int m = mg * 64 + ph * 32 + r2l;
        if (m >= 2016) break;
        f32x4 v = *reinterpret_cast<const f32x4*>(&LsF[r2l * 260 + lane * 4]);
        v += b4;
        const int sd = m >> 5, bb = m & 31;
        f32x4* dst = reinterpret_cast<f32x4*>(
            &out[(size_t)bb * kT * kV + (size_t)(sd + 1) * kV + nglob]);
        __builtin_nontemporal_store(v, dst);
      }
    }
  }
}

// ---- persistent recurrence, fence-free, TREE barrier.
// 512 blocks x 256 thr (R10's fast block shape: quad q x batch-half mt,
// 2 blocks/CU). Weights in VGPRs; c in registers; single-assignment h-seqs
// with agent-scope atomic h stores (bit-exact validated R11/R12).
// Barrier: arrival on 16 group counters (32 blocks each, distinct lines,
// parallel RMWs) -> last-arriver bumps ONE global counter -> one lane per
// block polls the global counter. Kills both measured contention modes
// (R11: 64K-load poll storm; R12: 256 same-line RMW arrivals).
struct RecurArgs {
  const unsigned short* wih1[2];  // enc, dec (cell layout)
  const unsigned short* whh1[2];
  const unsigned short* whh0[2];
  const unsigned short* xproj[2];  // cell-order bases
  const float* bsum1[2];           // cell-order combined L1 bias
  unsigned short* h0seq;  // 128 slots x 32768 elems (slot p = h0 state t=p-1)
  unsigned short* h1seq;  // 128 slots (slot p = h1 state t=p-1)
  int* xcnt;              // [128][16] group counters, stride 32 ints
  int* gcnt;              // [128] global counters, stride 32 ints
};

#define LOADW(dst, src)                                                      \
  {                                                                          \
    _Pragma("unroll") for (int s_ = 0; s_ < 8; ++s_) dst[s_] =               \
        *reinterpret_cast<const short8v*>((src) + wbase + (size_t)s_ * 512); \
  }

__global__ __launch_bounds__(256)
void lstm_persist(RecurArgs A) {
  const int bid = blockIdx.x;  // 0..511
  const int q = (bid & 7) * 32 + ((bid >> 3) >> 1);
  const int mt = (bid >> 3) & 1;
  const int grp = bid >> 5;  // 0..15
  const int tid = threadIdx.x;
  const int wave = tid >> 6;  // K-slice 0..3
  const int lane = tid & 63;
  const int ksb = wave * 8;
  // Ls[prod][wave][lane][r]; prod: 0=ih1, 1=hh1, 2=hh0
  __shared__ alignas(16) float Ls[3][4][64][4];  // 12 KB

  const size_t wbase = ((size_t)(q * 32 + ksb) * 64 + lane) * 8;
  short8v wI[8], wJ[8], wH[8];
  LOADW(wI, A.wih1[0]);
  LOADW(wJ, A.whh1[0]);
  LOADW(wH, A.whh0[0]);

  // epilogue-thread persistent state (tid < 64)
  const int mloc = tid >> 2;  // 0..15 valid when tid<64
  const int ul = tid & 3;
  const int m = mt * 16 + (mloc & 15);
  const int u = q * 4 + ul;
  float cold0 = 0.f, cold1 = 0.f;
  float bs[4] = {};
  if (tid < 64) {
#pragma unroll
    for (int g = 0; g < 4; ++g) bs[g] = A.bsum1[0][q * 16 + g * 4 + ul];
  }
  const int r = mloc & 3;
  const int lm = (mloc & 12) << 2;
  const int ksu = u >> 5;
  const int lane3 = (m & 15) | (((u >> 3) & 3) << 4);
  const int e = u & 7;
  const size_t fidx = (size_t)((mt * 32 + ksu) * 64 + lane3) * 8 + e;

  for (int p = 0; p < 128; ++p) {
    if (p == 64) LOADW(wH, A.whh0[1]);
    if (p == 65) {
      LOADW(wI, A.wih1[1]);
      LOADW(wJ, A.whh1[1]);
      if (tid < 64) {
#pragma unroll
        for (int g = 0; g < 4; ++g) bs[g] = A.bsum1[1][q * 16 + g * 4 + ul];
      }
    }
    // xproj prefetch for L0(p) (hidden under the MFMA phase)
    float xp[4] = {};
    if (tid < 64 && p <= 126) {
      const int e0 = (p < kT) ? 0 : 1;
      const unsigned short* xprojc =
          A.xproj[e0] + (size_t)(e0 ? (p - kT) : p) * kB * kG;
#pragma unroll
      for (int g = 0; g < 4; ++g)
        xp[g] = bf2f(xprojc[(q * 32 + m) * 16 + g * 4 + ul]);
    }

    const unsigned short* A0 = A.h0seq + (size_t)p * 32768;
    const unsigned short* A1 = A.h1seq + (size_t)(p > 0 ? p - 1 : 0) * 32768;

    f32x4 aI = {0.f, 0.f, 0.f, 0.f};
    f32x4 aJv = {0.f, 0.f, 0.f, 0.f};
    f32x4 aH = {0.f, 0.f, 0.f, 0.f};
#pragma unroll
    for (int s = 0; s < 8; ++s) {
      const int ks = ksb + s;
      const size_t aidx = (size_t)((mt * 32 + ks) * 64 + lane) * 8;
      const short8v a0 = *reinterpret_cast<const short8v*>(A0 + aidx);
      const short8v a1 = *reinterpret_cast<const short8v*>(A1 + aidx);
      aI = __builtin_amdgcn_mfma_f32_16x16x32_bf16(a0, wI[s], aI, 0, 0, 0);
      aJv = __builtin_amdgcn_mfma_f32_16x16x32_bf16(a1, wJ[s], aJv, 0, 0, 0);
      aH = __builtin_amdgcn_mfma_f32_16x16x32_bf16(a0, wH[s], aH, 0, 0, 0);
    }
    *reinterpret_cast<f32x4*>(&Ls[0][wave][lane][0]) = aI;
    *reinterpret_cast<f32x4*>(&Ls[1][wave][lane][0]) = aJv;
    *reinterpret_cast<f32x4*>(&Ls[2][wave][lane][0]) = aH;
    __syncthreads();

    if (tid < 64) {
      if (p <= 126) {  // L0(p)
        float g0[4];
#pragma unroll
        for (int g = 0; g < 4; ++g) {
          const int ln = (g * 4 + ul) | lm;
          g0[g] = Ls[2][0][ln][r] + Ls[2][1][ln][r] + Ls[2][2][ln][r] +
                  Ls[2][3][ln][r] + xp[g];
        }
        const float cnew = sigmoid_f(g0[1]) * cold0 + sigmoid_f(g0[0]) * tanhf(g0[2]);
        const float hnew = sigmoid_f(g0[3]) * tanhf(cnew);
        cold0 = cnew;
        const unsigned int hb = f2bf(hnew);
        const unsigned int other = __shfl_xor((int)hb, 1);
        if ((ul & 1) == 0) {
          unsigned int word = (hb & 0xffffu) | (other << 16);
          unsigned int* dst = reinterpret_cast<unsigned int*>(
              A.h0seq + (size_t)(p + 1) * 32768 + fidx);
          __hip_atomic_store(dst, word, __ATOMIC_RELAXED,
                             __HIP_MEMORY_SCOPE_AGENT);
        }
      }
      if (p >= 1) {  // L1(p-1)
        float g1[4];
#pragma unroll
        for (int g = 0; g < 4; ++g) {
          const int ln = (g * 4 + ul) | lm;
          g1[g] = Ls[0][0][ln][r] + Ls[0][1][ln][r] + Ls[0][2][ln][r] +
                  Ls[0][3][ln][r] + Ls[1][0][ln][r] + Ls[1][1][ln][r] +
                  Ls[1][2][ln][r] + Ls[1][3][ln][r] + bs[g];
        }
        const float cnew = sigmoid_f(g1[1]) * cold1 + sigmoid_f(g1[0]) * tanhf(g1[2]);
        const float hnew = sigmoid_f(g1[3]) * tanhf(cnew);
        cold1 = cnew;
        const unsigned int hb = f2bf(hnew);
        const unsigned int other = __shfl_xor((int)hb, 1);
        if ((ul & 1) == 0) {
          unsigned int word = (hb & 0xffffu) | (other << 16);
          unsigned int* dst = reinterpret_cast<unsigned int*>(
              A.h1seq + (size_t)p * 32768 + fidx);
          __hip_atomic_store(dst, word, __ATOMIC_RELAXED,
                             __HIP_MEMORY_SCOPE_AGENT);
        }
      }
    }

    // ---- tree barrier (fence-free) ----
    asm volatile("s_waitcnt vmcnt(0)" ::: "memory");  // h stores at L3
    __syncthreads();
    if (tid == 0) {
      const int a =
          __hip_atomic_fetch_add(&A.xcnt[(p * 16 + grp) * 32], 1,
                                 __ATOMIC_RELAXED, __HIP_MEMORY_SCOPE_AGENT);
      if (a == 31)
        __hip_atomic_fetch_add(&A.gcnt[p * 32], 1, __ATOMIC_RELAXED,
                               __HIP_MEMORY_SCOPE_AGENT);
      for (int guard = 0; guard < (1 << 14); ++guard) {
        const int v = __hip_atomic_load(&A.gcnt[p * 32], __ATOMIC_RELAXED,
                                        __HIP_MEMORY_SCOPE_AGENT);
        if (v >= 16) break;
        __builtin_amdgcn_s_sleep(1);
      }
    }
    __syncthreads();
  }
}

}  // namespace

extern "C" void kernel_launch(void* const* d_in, const int* in_sizes, int n_in,
                              void* d_out, int out_size, void* d_ws, size_t ws_size,
                              hipStream_t stream) {
  const int* input_ids = (const int*)d_in[0];
  const int* output_ids = (const int*)d_in[1];
  const float* enc_emb = (const float*)d_in[2];
  const float* enc_Wih = (const float*)d_in[3];
  const float* enc_Whh = (const float*)d_in[4];
  const float* enc_bih = (const float*)d_in[5];
  const float* enc_bhh = (const float*)d_in[6];
  const float* dec_emb = (const float*)d_in[7];
  const float* dec_Wih = (const float*)d_in[8];
  const float* dec_Whh = (const float*)d_in[9];
  const float* dec_bih = (const float*)d_in[10];
  const float* dec_bhh = (const float*)d_in[11];
  const float* Wout = (const float*)d_in[12];
  const float* bout = (const float*)d_in[13];
  float* out = (float*)d_out;
  char* ws = (char*)d_ws;

  const size_t WL = (size_t)kG * kH;  // per-layer weight stride (elems)

  // ---- workspace layout (bytes) ----
  size_t off = 0;
  unsigned short* wout_frag = (unsigned short*)(ws + 0);
  unsigned short* xproj_enc = (unsigned short*)(ws + off); off += (size_t)kT * kB * kG * 2;
  unsigned short* xin_enc = (unsigned short*)(ws + off);
  unsigned short* h0seq = xin_enc;  // alias (8.39 MB <= 12.58 MB region)
  off += (size_t)kT * kB * kH * 2;
  unsigned short* wih0_enc = (unsigned short*)(ws + off); off += WL * 2;
  unsigned short* wih0_dec = (unsigned short*)(ws + off); off += WL * 2;
  // persistent regions
  unsigned short* xproj_dec = (unsigned short*)(ws + off); off += (size_t)(kT - 1) * kB * kG * 2;
  unsigned short* xin_dec = (unsigned short*)(ws + off); off += (size_t)(kT - 1) * kB * kH * 2;
  unsigned short* h1seq = (unsigned short*)(ws + off); off += (size_t)128 * kB * kH * 2;
  unsigned short* wswz[6];
  for (int i = 0; i < 6; ++i) { wswz[i] = (unsigned short*)(ws + off); off += WL * 2; }
  float* bsum_enc = (float*)(ws + off); off += kG * 4;
  float* bsum_dec = (float*)(ws + off); off += kG * 4;
  int* xcnt = (int*)(ws + off); off += 128 * 16 * 32 * 4;
  int* gcnt = (int*)(ws + off); off += 128 * 32 * 4;

  // one-time weight conversions (single fused launch)
  ConvJobs C;
  C.src[0] = enc_Whh;       C.dst[0] = wswz[0];    C.mode[0] = 0;
  C.src[1] = enc_Wih + WL;  C.dst[1] = wswz[1];    C.mode[1] = 0;
  C.src[2] = enc_Whh + WL;  C.dst[2] = wswz[2];    C.mode[2] = 0;
  C.src[3] = dec_Whh;       C.dst[3] = wswz[3];    C.mode[3] = 0;
  C.src[4] = dec_Wih + WL;  C.dst[4] = wswz[4];    C.mode[4] = 0;
  C.src[5] = dec_Whh + WL;  C.dst[5] = wswz[5];    C.mode[5] = 0;
  C.src[6] = enc_Wih;       C.dst[6] = wih0_enc;   C.mode[6] = 1;
  C.src[7] = dec_Wih;       C.dst[7] = wih0_dec;   C.mode[7] = 1;
  conv8<<<8 * 2048, 256, 0, stream>>>(C);
  bias_cell<<<16, 256, 0, stream>>>(enc_bih + kG, enc_bhh + kG, bsum_enc);
  bias_cell<<<16, 256, 0, stream>>>(dec_bih + kG, dec_bhh + kG, bsum_dec);

  // gather embeddings into A-frag layout
  gather_frag<<<128 * 8, 256, 0, stream>>>(enc_emb, input_ids, xin_enc, 128);
  gather_frag<<<126 * 8, 256, 0, stream>>>(dec_emb, output_ids, xin_dec, 126);

  // layer-0 input projections (bias fused, bf16 cell-order out)
  proj_mfma<<<dim3(32, 32), 256, 0, stream>>>(xin_enc, wih0_enc, enc_bih, enc_bhh,
                                              xproj_enc, 128);
  proj_mfma<<<dim3(32, 32), 256, 0, stream>>>(xin_dec, wih0_dec, dec_bih, dec_bhh,
                                              xproj_dec, 126);

  // zero h0seq slot 0, h1seq slot 0, counters (AFTER proj: h0seq aliases xin_enc)
  (void)hipMemsetAsync(h0seq, 0, (size_t)kB * kH * 2, stream);
  (void)hipMemsetAsync(h1seq, 0, (size_t)kB * kH * 2, stream);
  (void)hipMemsetAsync(xcnt, 0, (128 * 16 * 32 + 128 * 32) * 4, stream);

  // ---- recurrence: ONE persistent fence-free kernel, 128 steps ----
  RecurArgs RA;
  RA.wih1[0] = wswz[1]; RA.wih1[1] = wswz[4];
  RA.whh1[0] = wswz[2]; RA.whh1[1] = wswz[5];
  RA.whh0[0] = wswz[0]; RA.whh0[1] = wswz[3];
  RA.xproj[0] = xproj_enc; RA.xproj[1] = xproj_dec;
  RA.bsum1[0] = bsum_enc; RA.bsum1[1] = bsum_dec;
  RA.h0seq = h0seq;
  RA.h1seq = h1seq;
  RA.xcnt = xcnt;
  RA.gcnt = gcnt;
  lstm_persist<<<512, 256, 0, stream>>>(RA);

  // Wout frags (aliases region A — runs after the recurrence)
  convert_frag<<<8000, 256, 0, stream>>>(Wout, wout_frag, kV * (kH / 8));

  // logits[:, 0, :]
  zero_t0_kernel<<<(kB * kV + 255) / 256, 256, 0, stream>>>(out);
  ones_t0_kernel<<<1, kB * kB, 0, stream>>>(output_ids, out);

  // logits[:, 1:, :] — htop IS h1seq slots 65..127 (126 m-tiles, contiguous)
  out_gemm_mfma<<<2016, 256, 0, stream>>>(h1seq + (size_t)65 * kB * kH,
                                          wout_frag, bout, out);
}

// Round 14
// 991.503 us; speedup vs baseline: 1.5221x; 1.2086x over previous
//
#include <hip/hip_runtime.h>

namespace {

constexpr int kB = 32;
constexpr int kT = 64;
constexpr int kH = 1024;
constexpr int kE = 1024;
constexpr int kV = 16000;
constexpr int kG = 4096;  // 4*H

typedef __attribute__((ext_vector_type(8))) short short8v;
typedef __attribute__((ext_vector_type(4))) float f32x4;

__device__ __forceinline__ float sigmoid_f(float x) {
  return 1.0f / (1.0f + __expf(-x));
}
__device__ __forceinline__ unsigned short f2bf(float x) {
  unsigned int u = __builtin_bit_cast(unsigned int, x);
  u = (u + 0x7FFFu + ((u >> 16) & 1u)) >> 16;
  return (unsigned short)u;
}
__device__ __forceinline__ float bf2f(unsigned short h) {
  return __builtin_bit_cast(float, (unsigned int)h << 16);
}

// ---------------- t=0 logits slice ----------------
__global__ void zero_t0_kernel(float* __restrict__ out) {
  int idx = blockIdx.x * blockDim.x + threadIdx.x;
  if (idx >= kB * kV) return;
  int b = idx / kV, v = idx % kV;
  __builtin_nontemporal_store(0.0f, &out[(size_t)b * kT * kV + v]);
}

// JAX outer-index semantics: out[b, 0, output_ids[j, 0]] = 1 for ALL (b, j)
__global__ void ones_t0_kernel(const int* __restrict__ output_ids,
                               float* __restrict__ out) {
  int b = threadIdx.x >> 5;
  int j = threadIdx.x & 31;
  int id = output_ids[j * kT];
  out[(size_t)b * kT * kV + id] = 1.0f;
}

// ---- fused one-time weight conversion: 8 matrices, mode 0=cell, 1=frag.
struct ConvJobs {
  const float* src[8];
  unsigned short* dst[8];
  int mode[8];
};
__global__ __launch_bounds__(256)
void conv8(ConvJobs C) {
  const int mat = blockIdx.x >> 11;
  const int idx = (blockIdx.x & 2047) * 256 + threadIdx.x;  // 0..524287
  const float* __restrict__ src = C.src[mat];
  unsigned short* __restrict__ dst = C.dst[mat];
  const int l = idx & 63;
  int row, k;
  if (C.mode[mat] == 0) {  // cell order
    const int kstep = (idx >> 6) & 31;
    const int uq = (idx >> 11) & 1;
    const int ub = idx >> 12;
    const int n = l & 15;
    row = (n >> 2) * kH + ub * 8 + uq * 4 + (n & 3);
    k = kstep * 32 + ((l >> 4) << 3);
  } else {  // frag order (16-row tiles)
    const int s = (idx >> 6) & 31;
    const int rg = idx >> 11;
    row = rg * 16 + (l & 15);
    k = s * 32 + ((l >> 4) << 3);
  }
  const float4* p = reinterpret_cast<const float4*>(src + (size_t)row * kH + k);
  float4 v0 = p[0], v1 = p[1];
  short8v o;
  o[0] = (short)f2bf(v0.x); o[1] = (short)f2bf(v0.y);
  o[2] = (short)f2bf(v0.z); o[3] = (short)f2bf(v0.w);
  o[4] = (short)f2bf(v1.x); o[5] = (short)f2bf(v1.y);
  o[6] = (short)f2bf(v1.z); o[7] = (short)f2bf(v1.w);
  *reinterpret_cast<short8v*>(dst + (size_t)idx * 8) = o;
}

// ---- convert fp32 row-major (R,1024) -> bf16 MFMA B-frag order (Wout).
__global__ __launch_bounds__(256)
void convert_frag(const float* __restrict__ src, unsigned short* __restrict__ dst,
                  int nchunks) {
  const int idx = blockIdx.x * 256 + threadIdx.x;
  if (idx >= nchunks) return;
  const int lane = idx & 63;
  const int s = (idx >> 6) & 31;
  const int rg = idx >> 11;
  const int row = rg * 16 + (lane & 15);
  const int k = s * 32 + ((lane >> 4) << 3);
  const float4* p = reinterpret_cast<const float4*>(src + (size_t)row * kH + k);
  float4 v0 = p[0], v1 = p[1];
  short8v o;
  o[0] = (short)f2bf(v0.x); o[1] = (short)f2bf(v0.y);
  o[2] = (short)f2bf(v0.z); o[3] = (short)f2bf(v0.w);
  o[4] = (short)f2bf(v1.x); o[5] = (short)f2bf(v1.y);
  o[6] = (short)f2bf(v1.z); o[7] = (short)f2bf(v1.w);
  *reinterpret_cast<short8v*>(dst + (size_t)idx * 8) = o;
}

// ---- combined L1 biases into cell order, enc+dec in one launch.
__global__ void bias_cell2(const float* __restrict__ bih_e,
                           const float* __restrict__ bhh_e,
                           float* __restrict__ dst_e,
                           const float* __restrict__ bih_d,
                           const float* __restrict__ bhh_d,
                           float* __restrict__ dst_d) {
  const int gi = blockIdx.x * 256 + threadIdx.x;
  const int which = gi >> 12;
  const int i = gi & 4095;
  if (which > 1) return;
  const float* bih = which ? bih_d : bih_e;
  const float* bhh = which ? bhh_d : bhh_e;
  float* dst = which ? dst_d : dst_e;
  const int g = i >> 10, u = i & 1023;
  dst[(u >> 2) * 16 + g * 4 + (u & 3)] = bih[i] + bhh[i];
}

// ---- gather embedding rows into A-frag bf16 layout.
__global__ __launch_bounds__(256)
void gather_frag(const float* __restrict__ emb, const int* __restrict__ ids,
                 unsigned short* __restrict__ dst, int ntiles) {
  const int idx = blockIdx.x * 256 + threadIdx.x;
  const int lane = idx & 63;
  const int s = (idx >> 6) & 31;
  const int tile = idx >> 11;
  if (tile >= ntiles) return;
  const int m = tile * 16 + (lane & 15);
  const int t = m >> 5, b = m & 31;
  const int id = ids[b * kT + t];
  const int k = s * 32 + ((lane >> 4) << 3);
  const float4* p = reinterpret_cast<const float4*>(emb + (size_t)id * kE + k);
  float4 v0 = p[0], v1 = p[1];
  short8v o;
  o[0] = (short)f2bf(v0.x); o[1] = (short)f2bf(v0.y);
  o[2] = (short)f2bf(v0.z); o[3] = (short)f2bf(v0.w);
  o[4] = (short)f2bf(v1.x); o[5] = (short)f2bf(v1.y);
  o[6] = (short)f2bf(v1.z); o[7] = (short)f2bf(v1.w);
  *reinterpret_cast<short8v*>(dst + (size_t)idx * 8) = o;
}

// ---- proj MFMA (enc+dec fused via blockIdx.z): xproj in CELL-ORDER
// [t][q][m 32][16 = g*4+uu] bf16, value = xin . W^T + b0 + b1.
struct ProjArgs {
  const unsigned short* Af[2];
  const unsigned short* Bf[2];
  const float* b0[2];
  const float* b1[2];
  unsigned short* dst[2];
  int nmt[2];
};
__global__ __launch_bounds__(256)
void proj_mfma2(ProjArgs P) {
  const int z = blockIdx.z;
  const unsigned short* __restrict__ Af = P.Af[z];
  const unsigned short* __restrict__ Bf = P.Bf[z];
  const float* __restrict__ b0 = P.b0[z];
  const float* __restrict__ b1 = P.b1[z];
  unsigned short* __restrict__ dst = P.dst[z];
  const int nmt = P.nmt[z];
  const int w = threadIdx.x >> 6, lane = threadIdx.x & 63;
  const int mg = blockIdx.x, ng = blockIdx.y;
  f32x4 acc[4][2] = {};
  const unsigned short* Ab[4];
  const unsigned short* Bb[2];
#pragma unroll
  for (int i = 0; i < 4; ++i) {
    int tile = mg * 4 + i;
    if (tile > nmt - 1) tile = nmt - 1;
    Ab[i] = Af + (size_t)tile * 16384 + lane * 8;
  }
#pragma unroll
  for (int j = 0; j < 2; ++j) {
    const int nt = ng * 8 + w * 2 + j;
    Bb[j] = Bf + (size_t)nt * 16384 + lane * 8;
  }
#pragma unroll 2
  for (int s = 0; s < 32; ++s) {
    short8v a[4], b[2];
#pragma unroll
    for (int i = 0; i < 4; ++i) a[i] = *reinterpret_cast<const short8v*>(Ab[i] + s * 512);
#pragma unroll
    for (int j = 0; j < 2; ++j) b[j] = *reinterpret_cast<const short8v*>(Bb[j] + s * 512);
#pragma unroll
    for (int i = 0; i < 4; ++i)
#pragma unroll
      for (int j = 0; j < 2; ++j)
        acc[i][j] = __builtin_amdgcn_mfma_f32_16x16x32_bf16(a[i], b[j], acc[i][j], 0, 0, 0);
  }
#pragma unroll
  for (int i = 0; i < 4; ++i) {
    const int tile = mg * 4 + i;
    if (tile >= nmt) continue;
    const int mbase = tile * 16 + ((lane >> 4) << 2);
#pragma unroll
    for (int j = 0; j < 2; ++j) {
      const int n = (ng * 8 + w * 2 + j) * 16 + (lane & 15);
      const float bj = b0[n] + b1[n];
      const int g = n >> 10;
      const int u = n & 1023;
      const int q = u >> 2;
      const int uu = u & 3;
#pragma unroll
      for (int r = 0; r < 4; ++r) {
        const int m2 = mbase + r;
        const int t = m2 >> 5, mb = m2 & 31;
        dst[(size_t)t * kB * kG + (size_t)(q * 32 + mb) * 16 + g * 4 + uu] =
            f2bf(acc[i][j][r] + bj);
      }
    }
  }
}

// ---- output GEMM MFMA (R10 known-good): XCD-swizzled 1-D grid; 4x4
// tiles/wave; two-pass 32-row LDS transpose epilogue -> f32x4 NT stores.
__global__ __launch_bounds__(256)
void out_gemm_mfma(const unsigned short* __restrict__ Af,
                   const unsigned short* __restrict__ Bf,
                   const float* __restrict__ bias, float* __restrict__ out) {
  const int w = threadIdx.x >> 6, lane = threadIdx.x & 63;
  const int bid = blockIdx.x;
  const int swz = (bid & 7) * 252 + (bid >> 3);
  const int mg = swz & 31, ng = swz >> 5;
  __shared__ float LsF[32 * 260];
  f32x4 acc[4][4] = {};
  const unsigned short* Ab[4];
  const unsigned short* Bb[4];
#pragma unroll
  for (int i = 0; i < 4; ++i) {
    int tile = mg * 4 + i;
    if (tile > 125) tile = 125;
    Ab[i] = Af + (size_t)tile * 16384 + lane * 8;
  }
#pragma unroll
  for (int j = 0; j < 4; ++j) {
    int nt = ng * 16 + w * 4 + j;
    if (nt > 999) nt = 999;
    Bb[j] = Bf + (size_t)nt * 16384 + lane * 8;
  }
#pragma unroll 2
  for (int s = 0; s < 32; ++s) {
    short8v a[4], b[4];
#pragma unroll
    for (int i = 0; i < 4; ++i) a[i] = *reinterpret_cast<const short8v*>(Ab[i] + s * 512);
#pragma unroll
    for (int j = 0; j < 4; ++j) b[j] = *reinterpret_cast<const short8v*>(Bb[j] + s * 512);
#pragma unroll
    for (int i = 0; i < 4; ++i)
#pragma unroll
      for (int j = 0; j < 4; ++j)
        acc[i][j] = __builtin_amdgcn_mfma_f32_16x16x32_bf16(a[i], b[j], acc[i][j], 0, 0, 0);
  }
  const int nglob = ng * 256 + lane * 4;
  f32x4 b4 = {0.f, 0.f, 0.f, 0.f};
  if (nglob < kV) b4 = *reinterpret_cast<const f32x4*>(&bias[nglob]);
#pragma unroll
  for (int ph = 0; ph < 2; ++ph) {
    if (ph) __syncthreads();
#pragma unroll
    for (int i2 = 0; i2 < 2; ++i2) {
      const int i = ph * 2 + i2;
      const int r2b = i2 * 16 + ((lane >> 4) << 2);
#pragma unroll
      for (int j = 0; j < 4; ++j) {
        const int nloc = (w * 4 + j) * 16 + (lane & 15);
#pragma unroll
        for (int r = 0; r < 4; ++r) LsF[(r2b + r) * 260 + nloc] = acc[i][j][r];
      }
    }
    __syncthreads();
    if (nglob < kV) {
#pragma unroll
      for (int it = 0; it < 8; ++it) {
        const int r2l = w * 8 + it;
        const int m = mg * 64 + ph * 32 + r2l;
        if (m >= 2016) break;
        f32x4 v = *reinterpret_cast<const f32x4*>(&LsF[r2l * 260 + lane * 4]);
        v += b4;
        const int sd = m >> 5, bb = m & 31;
        f32x4* dst = reinterpret_cast<f32x4*>(
            &out[(size_t)bb * kT * kV + (size_t)(sd + 1) * kV + nglob]);
        __builtin_nontemporal_store(v, dst);
      }
    }
  }
}

// ---- fused pair step (R10 known-good shape): 512 blocks x 256 thr;
// block = (quad q, batch-half mt), XCD-pinned. A-loads hoisted ahead of
// B/MFMA loop so cross-XCD h latency overlaps local-L2 B loads + MFMA.
struct CellJob {
  const unsigned short* A0;      // H0[p-1] frags
  const unsigned short* A1;      // H1[p-2] frags
  const unsigned short* Wih1;    // cell layout
  const unsigned short* Whh1;
  const unsigned short* Whh0;
  const unsigned short* xprojc;  // cell-order slice for L0(p)
  const float* bsum1;            // cell-order combined L1 bias [q*16+g*4+ul]
  float* c0;
  float* c1;
  unsigned short* h0_out;
  unsigned short* h1_out;
  unsigned short* htop_out;      // or null
  int has_l0, has_l1;
};

__global__ __launch_bounds__(256)
void lstm_pair(CellJob J) {
  const int bid = blockIdx.x;                 // 0..511
  const int q = (bid & 7) * 32 + ((bid >> 3) >> 1);
  const int mt = (bid >> 3) & 1;
  const int tid = threadIdx.x;
  const int wave = tid >> 6;                  // K-slice 0..3
  const int lane = tid & 63;
  // Ls[prod][wave][lane][r]; prod: 0=ih1, 1=hh1, 2=hh0
  __shared__ alignas(16) float Ls[3][4][64][4];  // 12 KB

  const int ksb = wave * 8;

  // ---- issue the 16 long-latency A loads FIRST (cross-XCD L3) ----
  short8v a0r[8], a1r[8];
#pragma unroll
  for (int s = 0; s < 8; ++s) {
    const int ks = ksb + s;
    const size_t aidx = (size_t)((mt * 32 + ks) * 64 + lane) * 8;
    a0r[s] = *reinterpret_cast<const short8v*>(J.A0 + aidx);
    a1r[s] = *reinterpret_cast<const short8v*>(J.A1 + aidx);
  }

  // ---- epilogue operand prefetch (overlaps with A latency) ----
  const int mloc = tid >> 2;  // valid for tid<64
  const int ul = tid & 3;
  const int m = mt * 16 + (mloc & 15);
  const int u = q * 4 + ul;
  float cold0 = 0.f, cold1 = 0.f;
  float xp[4] = {}, bs[4] = {};
  if (tid < 64) {
    cold0 = J.c0[m * kH + u];
    cold1 = J.c1[m * kH + u];
#pragma unroll
    for (int g = 0; g < 4; ++g) {
      xp[g] = bf2f(J.xprojc[(q * 32 + m) * 16 + g * 4 + ul]);
      bs[g] = J.bsum1[q * 16 + g * 4 + ul];
    }
  }

  // ---- B loads (local-XCD L2) + MFMA ----
  f32x4 aI = {0.f, 0.f, 0.f, 0.f};
  f32x4 aJv = {0.f, 0.f, 0.f, 0.f};
  f32x4 aH = {0.f, 0.f, 0.f, 0.f};
#pragma unroll
  for (int s = 0; s < 8; ++s) {
    const int ks = ksb + s;
    const size_t widx = ((size_t)(q * 32 + ks) * 64 + lane) * 8;
    const short8v bi = *reinterpret_cast<const short8v*>(J.Wih1 + widx);
    const short8v bh1 = *reinterpret_cast<const short8v*>(J.Whh1 + widx);
    const short8v bh0 = *reinterpret_cast<const short8v*>(J.Whh0 + widx);
    aI = __builtin_amdgcn_mfma_f32_16x16x32_bf16(a0r[s], bi, aI, 0, 0, 0);
    aJv = __builtin_amdgcn_mfma_f32_16x16x32_bf16(a1r[s], bh1, aJv, 0, 0, 0);
    aH = __builtin_amdgcn_mfma_f32_16x16x32_bf16(a0r[s], bh0, aH, 0, 0, 0);
  }
  *reinterpret_cast<f32x4*>(&Ls[0][wave][lane][0]) = aI;
  *reinterpret_cast<f32x4*>(&Ls[1][wave][lane][0]) = aJv;
  *reinterpret_cast<f32x4*>(&Ls[2][wave][lane][0]) = aH;
  __syncthreads();

  if (tid < 64) {
    const int r = mloc & 3;
    const int lm = (mloc & 12) << 2;
    const int ksu = u >> 5;
    const int lane3 = (m & 15) | (((u >> 3) & 3) << 4);
    const int e = u & 7;
    const size_t fidx = (size_t)((mt * 32 + ksu) * 64 + lane3) * 8 + e;

    if (J.has_l0) {
      float g0[4];
#pragma unroll
      for (int g = 0; g < 4; ++g) {
        const int ln = (g * 4 + ul) | lm;
        g0[g] = Ls[2][0][ln][r] + Ls[2][1][ln][r] + Ls[2][2][ln][r] +
                Ls[2][3][ln][r] + xp[g];
      }
      const float cnew = sigmoid_f(g0[1]) * cold0 + sigmoid_f(g0[0]) * tanhf(g0[2]);
      const float hnew = sigmoid_f(g0[3]) * tanhf(cnew);
      J.c0[m * kH + u] = cnew;
      J.h0_out[fidx] = f2bf(hnew);
    }
    if (J.has_l1) {
      float g1[4];
#pragma unroll
      for (int g = 0; g < 4; ++g) {
        const int ln = (g * 4 + ul) | lm;
        g1[g] = Ls[0][0][ln][r] + Ls[0][1][ln][r] + Ls[0][2][ln][r] +
                Ls[0][3][ln][r] + Ls[1][0][ln][r] + Ls[1][1][ln][r] +
                Ls[1][2][ln][r] + Ls[1][3][ln][r] + bs[g];
      }
      const float cnew = sigmoid_f(g1[1]) * cold1 + sigmoid_f(g1[0]) * tanhf(g1[2]);
      const float hnew = sigmoid_f(g1[3]) * tanhf(cnew);
      J.c1[m * kH + u] = cnew;
      const unsigned short hb = f2bf(hnew);
      J.h1_out[fidx] = hb;
      if (J.htop_out) J.htop_out[fidx] = hb;
    }
  }
}

}  // namespace

extern "C" void kernel_launch(void* const* d_in, const int* in_sizes, int n_in,
                              void* d_out, int out_size, void* d_ws, size_t ws_size,
                              hipStream_t stream) {
  const int* input_ids = (const int*)d_in[0];
  const int* output_ids = (const int*)d_in[1];
  const float* enc_emb = (const float*)d_in[2];
  const float* enc_Wih = (const float*)d_in[3];
  const float* enc_Whh = (const float*)d_in[4];
  const float* enc_bih = (const float*)d_in[5];
  const float* enc_bhh = (const float*)d_in[6];
  const float* dec_emb = (const float*)d_in[7];
  const float* dec_Wih = (const float*)d_in[8];
  const float* dec_Whh = (const float*)d_in[9];
  const float* dec_bih = (const float*)d_in[10];
  const float* dec_bhh = (const float*)d_in[11];
  const float* Wout = (const float*)d_in[12];
  const float* bout = (const float*)d_in[13];
  float* out = (float*)d_out;
  char* ws = (char*)d_ws;

  const size_t WL = (size_t)kG * kH;  // per-layer weight stride (elems)

  // ---- workspace layout (bytes) ----
  size_t off = 0;
  // Region dead after encoder; Wout frags alias here (32.77 MB < 37.75 MB)
  unsigned short* wout_frag = (unsigned short*)(ws + 0);
  unsigned short* xproj_enc = (unsigned short*)(ws + off); off += (size_t)kT * kB * kG * 2;
  unsigned short* xin_enc = (unsigned short*)(ws + off); off += (size_t)kT * kB * kH * 2;
  unsigned short* wih0_enc = (unsigned short*)(ws + off); off += WL * 2;
  unsigned short* wih0_dec = (unsigned short*)(ws + off); off += WL * 2;
  // persistent regions
  unsigned short* xproj_dec = (unsigned short*)(ws + off); off += (size_t)(kT - 1) * kB * kG * 2;
  unsigned short* xin_dec = (unsigned short*)(ws + off); off += (size_t)(kT - 1) * kB * kH * 2;
  unsigned short* htop_frag = xin_dec;  // alias: xin_dec dead before decoder starts
  float* c0 = (float*)(ws + off); off += (size_t)kB * kH * 4;
  float* c1 = (float*)(ws + off); off += (size_t)kB * kH * 4;
  unsigned short* h0swz[2];
  unsigned short* h1swz[2];
  h0swz[0] = (unsigned short*)(ws + off); off += (size_t)kB * kH * 2;
  h0swz[1] = (unsigned short*)(ws + off); off += (size_t)kB * kH * 2;
  h1swz[0] = (unsigned short*)(ws + off); off += (size_t)kB * kH * 2;
  h1swz[1] = (unsigned short*)(ws + off); off += (size_t)kB * kH * 2;
  unsigned short* wswz[6];
  for (int i = 0; i < 6; ++i) { wswz[i] = (unsigned short*)(ws + off); off += WL * 2; }
  float* bsum_enc = (float*)(ws + off); off += kG * 4;
  float* bsum_dec = (float*)(ws + off); off += kG * 4;

  // zero c0,c1 + h frag ping-pong buffers (contiguous)
  (void)hipMemsetAsync(c0, 0, (size_t)kB * kH * (4 + 4 + 2 + 2 + 2 + 2), stream);

  // one-time weight conversions (single fused launch)
  ConvJobs C;
  C.src[0] = enc_Whh;       C.dst[0] = wswz[0];    C.mode[0] = 0;
  C.src[1] = enc_Wih + WL;  C.dst[1] = wswz[1];    C.mode[1] = 0;
  C.src[2] = enc_Whh + WL;  C.dst[2] = wswz[2];    C.mode[2] = 0;
  C.src[3] = dec_Whh;       C.dst[3] = wswz[3];    C.mode[3] = 0;
  C.src[4] = dec_Wih + WL;  C.dst[4] = wswz[4];    C.mode[4] = 0;
  C.src[5] = dec_Whh + WL;  C.dst[5] = wswz[5];    C.mode[5] = 0;
  C.src[6] = enc_Wih;       C.dst[6] = wih0_enc;   C.mode[6] = 1;
  C.src[7] = dec_Wih;       C.dst[7] = wih0_dec;   C.mode[7] = 1;
  conv8<<<8 * 2048, 256, 0, stream>>>(C);
  bias_cell2<<<32, 256, 0, stream>>>(enc_bih + kG, enc_bhh + kG, bsum_enc,
                                     dec_bih + kG, dec_bhh + kG, bsum_dec);

  // gather embeddings into A-frag layout
  gather_frag<<<128 * 8, 256, 0, stream>>>(enc_emb, input_ids, xin_enc, 128);
  gather_frag<<<126 * 8, 256, 0, stream>>>(dec_emb, output_ids, xin_dec, 126);

  // layer-0 input projections, enc+dec in ONE launch (bias fused, cell-order)
  ProjArgs P;
  P.Af[0] = xin_enc;  P.Bf[0] = wih0_enc; P.b0[0] = enc_bih; P.b1[0] = enc_bhh;
  P.dst[0] = xproj_enc; P.nmt[0] = 128;
  P.Af[1] = xin_dec;  P.Bf[1] = wih0_dec; P.b0[1] = dec_bih; P.b1[1] = dec_bhh;
  P.dst[1] = xproj_dec; P.nmt[1] = 126;
  proj_mfma2<<<dim3(32, 32, 2), 256, 0, stream>>>(P);

  // ---- recurrence: launch p runs L1(p-1) and L0(p); 128 identical launches.
  for (int p = 0; p <= 127; ++p) {
    CellJob J = {};
    J.has_l0 = (p <= 126);
    J.has_l1 = (p >= 1);
    J.A0 = h0swz[p & 1];          // H0[p-1]
    J.A1 = h1swz[(p + 1) & 1];    // H1[p-2]
    J.c0 = c0;
    J.c1 = c1;
    J.h0_out = h0swz[(p + 1) & 1];
    J.h1_out = h1swz[p & 1];
    // L0(p) operands (valid pointers even when gated off)
    if (p <= 126) {
      J.Whh0 = (p < kT) ? wswz[0] : wswz[3];
      J.xprojc = (p < kT) ? (xproj_enc + (size_t)p * kB * kG)
                          : (xproj_dec + (size_t)(p - kT) * kB * kG);
    } else {
      J.Whh0 = wswz[3];
      J.xprojc = xproj_dec;
    }
    // L1(p-1) operands
    const bool e1 = (p - 1) < kT;
    J.Wih1 = (p >= 1 && !e1) ? wswz[4] : wswz[1];
    J.Whh1 = (p >= 1 && !e1) ? wswz[5] : wswz[2];
    J.bsum1 = (p >= 1 && !e1) ? bsum_dec : bsum_enc;
    J.htop_out = (p >= 1 && (p - 1) >= kT)
                     ? (htop_frag + (size_t)(p - 1 - kT) * kB * kH)
                     : nullptr;
    lstm_pair<<<512, 256, 0, stream>>>(J);
    if (p == 63) {
      // enc xproj fully consumed -> build Wout frags in the aliased region
      convert_frag<<<8000, 256, 0, stream>>>(Wout, wout_frag, kV * (kH / 8));
    }
  }

  // logits[:, 0, :]
  zero_t0_kernel<<<(kB * kV + 255) / 256, 256, 0, stream>>>(out);
  ones_t0_kernel<<<1, kB * kB, 0, stream>>>(output_ids, out);

  // logits[:, 1:, :]
  out_gemm_mfma<<<2016, 256, 0, stream>>>(htop_frag, wout_frag, bout, out);
}

// Round 15
// 986.221 us; speedup vs baseline: 1.5303x; 1.0054x over previous
//
#include <hip/hip_runtime.h>

namespace {

constexpr int kB = 32;
constexpr int kT = 64;
constexpr int kH = 1024;
constexpr int kE = 1024;
constexpr int kV = 16000;
constexpr int kG = 4096;  // 4*H

typedef __attribute__((ext_vector_type(8))) short short8v;
typedef __attribute__((ext_vector_type(4))) float f32x4;

__device__ __forceinline__ float sigmoid_f(float x) {
  return 1.0f / (1.0f + __expf(-x));
}
__device__ __forceinline__ unsigned short f2bf(float x) {
  unsigned int u = __builtin_bit_cast(unsigned int, x);
  u = (u + 0x7FFFu + ((u >> 16) & 1u)) >> 16;
  return (unsigned short)u;
}
__device__ __forceinline__ float bf2f(unsigned short h) {
  return __builtin_bit_cast(float, (unsigned int)h << 16);
}

// ---- logits[:, 0, :] in ONE kernel: zeros + JAX outer-index ones
// (out[b,0,v] = 1 iff v == output_ids[j,0] for ANY j).
__global__ __launch_bounds__(256)
void init_t0(const int* __restrict__ output_ids, float* __restrict__ out) {
  __shared__ int ids[32];
  if (threadIdx.x < 32) ids[threadIdx.x] = output_ids[threadIdx.x * kT];
  __syncthreads();
  const int idx = blockIdx.x * 256 + threadIdx.x;
  if (idx >= kB * kV) return;
  const int b = idx / kV, v = idx % kV;
  float val = 0.f;
#pragma unroll
  for (int j = 0; j < 32; ++j) val = (v == ids[j]) ? 1.0f : val;
  __builtin_nontemporal_store(val, &out[(size_t)b * kT * kV + v]);
}

// ---- fused one-time conversion: 8 weight matrices + 2 embedding gathers.
// mode 0 = cell order, 1 = frag order, 2 = gather (frag order, row via ids).
struct ConvJobs {
  const float* src[10];
  unsigned short* dst[10];
  const int* ids[10];
  int mode[10];
  int ntiles[10];  // mode 2 bound
};
__global__ __launch_bounds__(256)
void conv10(ConvJobs C) {
  const int mat = blockIdx.x >> 11;
  const int idx = (blockIdx.x & 2047) * 256 + threadIdx.x;  // 0..524287
  const float* __restrict__ src = C.src[mat];
  unsigned short* __restrict__ dst = C.dst[mat];
  const int l = idx & 63;
  const int mode = C.mode[mat];
  int row, k;
  if (mode == 0) {  // cell order
    const int kstep = (idx >> 6) & 31;
    const int uq = (idx >> 11) & 1;
    const int ub = idx >> 12;
    const int n = l & 15;
    row = (n >> 2) * kH + ub * 8 + uq * 4 + (n & 3);
    k = kstep * 32 + ((l >> 4) << 3);
  } else {  // frag order (16-row tiles); mode 2 = gather via ids
    const int s = (idx >> 6) & 31;
    const int tile = idx >> 11;
    if (mode == 2) {
      if (tile >= C.ntiles[mat]) return;
      const int m = tile * 16 + (l & 15);
      row = C.ids[mat][(m & 31) * kT + (m >> 5)];
    } else {
      row = tile * 16 + (l & 15);
    }
    k = s * 32 + ((l >> 4) << 3);
  }
  const float4* p = reinterpret_cast<const float4*>(src + (size_t)row * kH + k);
  float4 v0 = p[0], v1 = p[1];
  short8v o;
  o[0] = (short)f2bf(v0.x); o[1] = (short)f2bf(v0.y);
  o[2] = (short)f2bf(v0.z); o[3] = (short)f2bf(v0.w);
  o[4] = (short)f2bf(v1.x); o[5] = (short)f2bf(v1.y);
  o[6] = (short)f2bf(v1.z); o[7] = (short)f2bf(v1.w);
  *reinterpret_cast<short8v*>(dst + (size_t)idx * 8) = o;
}

// ---- convert fp32 row-major (R,1024) -> bf16 MFMA B-frag order (Wout).
__global__ __launch_bounds__(256)
void convert_frag(const float* __restrict__ src, unsigned short* __restrict__ dst,
                  int nchunks) {
  const int idx = blockIdx.x * 256 + threadIdx.x;
  if (idx >= nchunks) return;
  const int lane = idx & 63;
  const int s = (idx >> 6) & 31;
  const int rg = idx >> 11;
  const int row = rg * 16 + (lane & 15);
  const int k = s * 32 + ((lane >> 4) << 3);
  const float4* p = reinterpret_cast<const float4*>(src + (size_t)row * kH + k);
  float4 v0 = p[0], v1 = p[1];
  short8v o;
  o[0] = (short)f2bf(v0.x); o[1] = (short)f2bf(v0.y);
  o[2] = (short)f2bf(v0.z); o[3] = (short)f2bf(v0.w);
  o[4] = (short)f2bf(v1.x); o[5] = (short)f2bf(v1.y);
  o[6] = (short)f2bf(v1.z); o[7] = (short)f2bf(v1.w);
  *reinterpret_cast<short8v*>(dst + (size_t)idx * 8) = o;
}

// ---- combined L1 biases into cell order, enc+dec in one launch.
__global__ void bias_cell2(const float* __restrict__ bih_e,
                           const float* __restrict__ bhh_e,
                           float* __restrict__ dst_e,
                           const float* __restrict__ bih_d,
                           const float* __restrict__ bhh_d,
                           float* __restrict__ dst_d) {
  const int gi = blockIdx.x * 256 + threadIdx.x;
  const int which = gi >> 12;
  const int i = gi & 4095;
  if (which > 1) return;
  const float* bih = which ? bih_d : bih_e;
  const float* bhh = which ? bhh_d : bhh_e;
  float* dst = which ? dst_d : dst_e;
  const int g = i >> 10, u = i & 1023;
  dst[(u >> 2) * 16 + g * 4 + (u & 3)] = bih[i] + bhh[i];
}

// ---- proj MFMA (enc+dec fused via blockIdx.z): xproj in CELL-ORDER
// [t][q][m 32][16 = g*4+uu] bf16, value = xin . W^T + b0 + b1.
struct ProjArgs {
  const unsigned short* Af[2];
  const unsigned short* Bf[2];
  const float* b0[2];
  const float* b1[2];
  unsigned short* dst[2];
  int nmt[2];
};
__global__ __launch_bounds__(256)
void proj_mfma2(ProjArgs P) {
  const int z = blockIdx.z;
  const unsigned short* __restrict__ Af = P.Af[z];
  const unsigned short* __restrict__ Bf = P.Bf[z];
  const float* __restrict__ b0 = P.b0[z];
  const float* __restrict__ b1 = P.b1[z];
  unsigned short* __restrict__ dst = P.dst[z];
  const int nmt = P.nmt[z];
  const int w = threadIdx.x >> 6, lane = threadIdx.x & 63;
  const int mg = blockIdx.x, ng = blockIdx.y;
  f32x4 acc[4][2] = {};
  const unsigned short* Ab[4];
  const unsigned short* Bb[2];
#pragma unroll
  for (int i = 0; i < 4; ++i) {
    int tile = mg * 4 + i;
    if (tile > nmt - 1) tile = nmt - 1;
    Ab[i] = Af + (size_t)tile * 16384 + lane * 8;
  }
#pragma unroll
  for (int j = 0; j < 2; ++j) {
    const int nt = ng * 8 + w * 2 + j;
    Bb[j] = Bf + (size_t)nt * 16384 + lane * 8;
  }
#pragma unroll 2
  for (int s = 0; s < 32; ++s) {
    short8v a[4], b[2];
#pragma unroll
    for (int i = 0; i < 4; ++i) a[i] = *reinterpret_cast<const short8v*>(Ab[i] + s * 512);
#pragma unroll
    for (int j = 0; j < 2; ++j) b[j] = *reinterpret_cast<const short8v*>(Bb[j] + s * 512);
#pragma unroll
    for (int i = 0; i < 4; ++i)
#pragma unroll
      for (int j = 0; j < 2; ++j)
        acc[i][j] = __builtin_amdgcn_mfma_f32_16x16x32_bf16(a[i], b[j], acc[i][j], 0, 0, 0);
  }
#pragma unroll
  for (int i = 0; i < 4; ++i) {
    const int tile = mg * 4 + i;
    if (tile >= nmt) continue;
    const int mbase = tile * 16 + ((lane >> 4) << 2);
#pragma unroll
    for (int j = 0; j < 2; ++j) {
      const int n = (ng * 8 + w * 2 + j) * 16 + (lane & 15);
      const float bj = b0[n] + b1[n];
      const int g = n >> 10;
      const int u = n & 1023;
      const int q = u >> 2;
      const int uu = u & 3;
#pragma unroll
      for (int r = 0; r < 4; ++r) {
        const int m2 = mbase + r;
        const int t = m2 >> 5, mb = m2 & 31;
        dst[(size_t)t * kB * kG + (size_t)(q * 32 + mb) * 16 + g * 4 + uu] =
            f2bf(acc[i][j][r] + bj);
      }
    }
  }
}

// ---- output GEMM MFMA: XCD-swizzled 1-D grid; 4x4 tiles/wave; two-pass
// 32-row LDS transpose epilogue -> f32x4 NT stores. unroll 4 for ILP.
__global__ __launch_bounds__(256)
void out_gemm_mfma(const unsigned short* __restrict__ Af,
                   const unsigned short* __restrict__ Bf,
                   const float* __restrict__ bias, float* __restrict__ out) {
  const int w = threadIdx.x >> 6, lane = threadIdx.x & 63;
  const int bid = blockIdx.x;
  const int swz = (bid & 7) * 252 + (bid >> 3);
  const int mg = swz & 31, ng = swz >> 5;
  __shared__ float LsF[32 * 260];
  f32x4 acc[4][4] = {};
  const unsigned short* Ab[4];
  const unsigned short* Bb[4];
#pragma unroll
  for (int i = 0; i < 4; ++i) {
    int tile = mg * 4 + i;
    if (tile > 125) tile = 125;
    Ab[i] = Af + (size_t)tile * 16384 + lane * 8;
  }
#pragma unroll
  for (int j = 0; j < 4; ++j) {
    int nt = ng * 16 + w * 4 + j;
    if (nt > 999) nt = 999;
    Bb[j] = Bf + (size_t)nt * 16384 + lane * 8;
  }
#pragma unroll 4
  for (int s = 0; s < 32; ++s) {
    short8v a[4], b[4];
#pragma unroll
    for (int i = 0; i < 4; ++i) a[i] = *reinterpret_cast<const short8v*>(Ab[i] + s * 512);
#pragma unroll
    for (int j = 0; j < 4; ++j) b[j] = *reinterpret_cast<const short8v*>(Bb[j] + s * 512);
#pragma unroll
    for (int i = 0; i < 4; ++i)
#pragma unroll
      for (int j = 0; j < 4; ++j)
        acc[i][j] = __builtin_amdgcn_mfma_f32_16x16x32_bf16(a[i], b[j], acc[i][j], 0, 0, 0);
  }
  const int nglob = ng * 256 + lane * 4;
  f32x4 b4 = {0.f, 0.f, 0.f, 0.f};
  if (nglob < kV) b4 = *reinterpret_cast<const f32x4*>(&bias[nglob]);
#pragma unroll
  for (int ph = 0; ph < 2; ++ph) {
    if (ph) __syncthreads();
#pragma unroll
    for (int i2 = 0; i2 < 2; ++i2) {
      const int i = ph * 2 + i2;
      const int r2b = i2 * 16 + ((lane >> 4) << 2);
#pragma unroll
      for (int j = 0; j < 4; ++j) {
        const int nloc = (w * 4 + j) * 16 + (lane & 15);
#pragma unroll
        for (int r = 0; r < 4; ++r) LsF[(r2b + r) * 260 + nloc] = acc[i][j][r];
      }
    }
    __syncthreads();
    if (nglob < kV) {
#pragma unroll
      for (int it = 0; it < 8; ++it) {
        const int r2l = w * 8 + it;
        const int m = mg * 64 + ph * 32 + r2l;
        if (m >= 2016) break;
        f32x4 v = *reinterpret_cast<const f32x4*>(&LsF[r2l * 260 + lane * 4]);
        v += b4;
        const int sd = m >> 5, bb = m & 31;
        f32x4* dst = reinterpret_cast<f32x4*>(
            &out[(size_t)bb * kT * kV + (size_t)(sd + 1) * kV + nglob]);
        __builtin_nontemporal_store(v, dst);
      }
    }
  }
}

// ---- fused pair step: 512 blocks x 256 thr; block = (quad q, batch-half mt),
// XCD-pinned. A-loads hoisted; decoder h1 routed directly into htop slots.
struct CellJob {
  const unsigned short* A0;      // H0[p-1] frags
  const unsigned short* A1;      // H1[p-2] frags
  const unsigned short* Wih1;    // cell layout
  const unsigned short* Whh1;
  const unsigned short* Whh0;
  const unsigned short* xprojc;  // cell-order slice for L0(p)
  const float* bsum1;            // cell-order combined L1 bias [q*16+g*4+ul]
  float* c0;
  float* c1;
  unsigned short* h0_out;
  unsigned short* h1_out;        // encoder: ping-pong; decoder: htop slot
  int has_l0, has_l1;
};

__global__ __launch_bounds__(256)
void lstm_pair(CellJob J) {
  const int bid = blockIdx.x;                 // 0..511
  const int q = (bid & 7) * 32 + ((bid >> 3) >> 1);
  const int mt = (bid >> 3) & 1;
  const int tid = threadIdx.x;
  const int wave = tid >> 6;                  // K-slice 0..3
  const int lane = tid & 63;
  // Ls[prod][wave][lane][r]; prod: 0=ih1, 1=hh1, 2=hh0
  __shared__ alignas(16) float Ls[3][4][64][4];  // 12 KB

  const int ksb = wave * 8;

  // ---- issue the 16 long-latency A loads FIRST (cross-XCD L3) ----
  short8v a0r[8], a1r[8];
#pragma unroll
  for (int s = 0; s < 8; ++s) {
    const int ks = ksb + s;
    const size_t aidx = (size_t)((mt * 32 + ks) * 64 + lane) * 8;
    a0r[s] = *reinterpret_cast<const short8v*>(J.A0 + aidx);
    a1r[s] = *reinterpret_cast<const short8v*>(J.A1 + aidx);
  }

  // ---- epilogue operand prefetch (overlaps with A latency) ----
  const int mloc = tid >> 2;  // valid for tid<64
  const int ul = tid & 3;
  const int m = mt * 16 + (mloc & 15);
  const int u = q * 4 + ul;
  float cold0 = 0.f, cold1 = 0.f;
  float xp[4] = {}, bs[4] = {};
  if (tid < 64) {
    cold0 = J.c0[m * kH + u];
    cold1 = J.c1[m * kH + u];
#pragma unroll
    for (int g = 0; g < 4; ++g) {
      xp[g] = bf2f(J.xprojc[(q * 32 + m) * 16 + g * 4 + ul]);
      bs[g] = J.bsum1[q * 16 + g * 4 + ul];
    }
  }

  // ---- B loads (local-XCD L2) + MFMA ----
  f32x4 aI = {0.f, 0.f, 0.f, 0.f};
  f32x4 aJv = {0.f, 0.f, 0.f, 0.f};
  f32x4 aH = {0.f, 0.f, 0.f, 0.f};
#pragma unroll
  for (int s = 0; s < 8; ++s) {
    const int ks = ksb + s;
    const size_t widx = ((size_t)(q * 32 + ks) * 64 + lane) * 8;
    const short8v bi = *reinterpret_cast<const short8v*>(J.Wih1 + widx);
    const short8v bh1 = *reinterpret_cast<const short8v*>(J.Whh1 + widx);
    const short8v bh0 = *reinterpret_cast<const short8v*>(J.Whh0 + widx);
    aI = __builtin_amdgcn_mfma_f32_16x16x32_bf16(a0r[s], bi, aI, 0, 0, 0);
    aJv = __builtin_amdgcn_mfma_f32_16x16x32_bf16(a1r[s], bh1, aJv, 0, 0, 0);
    aH = __builtin_amdgcn_mfma_f32_16x16x32_bf16(a0r[s], bh0, aH, 0, 0, 0);
  }
  *reinterpret_cast<f32x4*>(&Ls[0][wave][lane][0]) = aI;
  *reinterpret_cast<f32x4*>(&Ls[1][wave][lane][0]) = aJv;
  *reinterpret_cast<f32x4*>(&Ls[2][wave][lane][0]) = aH;
  __syncthreads();

  if (tid < 64) {
    const int r = mloc & 3;
    const int lm = (mloc & 12) << 2;
    const int ksu = u >> 5;
    const int lane3 = (m & 15) | (((u >> 3) & 3) << 4);
    const int e = u & 7;
    const size_t fidx = (size_t)((mt * 32 + ksu) * 64 + lane3) * 8 + e;

    if (J.has_l0) {
      float g0[4];
#pragma unroll
      for (int g = 0; g < 4; ++g) {
        const int ln = (g * 4 + ul) | lm;
        g0[g] = Ls[2][0][ln][r] + Ls[2][1][ln][r] + Ls[2][2][ln][r] +
                Ls[2][3][ln][r] + xp[g];
      }
      const float cnew = sigmoid_f(g0[1]) * cold0 + sigmoid_f(g0[0]) * tanhf(g0[2]);
      const float hnew = sigmoid_f(g0[3]) * tanhf(cnew);
      J.c0[m * kH + u] = cnew;
      J.h0_out[fidx] = f2bf(hnew);
    }
    if (J.has_l1) {
      float g1[4];
#pragma unroll
      for (int g = 0; g < 4; ++g) {
        const int ln = (g * 4 + ul) | lm;
        g1[g] = Ls[0][0][ln][r] + Ls[0][1][ln][r] + Ls[0][2][ln][r] +
                Ls[0][3][ln][r] + Ls[1][0][ln][r] + Ls[1][1][ln][r] +
                Ls[1][2][ln][r] + Ls[1][3][ln][r] + bs[g];
      }
      const float cnew = sigmoid_f(g1[1]) * cold1 + sigmoid_f(g1[0]) * tanhf(g1[2]);
      const float hnew = sigmoid_f(g1[3]) * tanhf(cnew);
      J.c1[m * kH + u] = cnew;
      J.h1_out[fidx] = f2bf(hnew);
    }
  }
}

}  // namespace

extern "C" void kernel_launch(void* const* d_in, const int* in_sizes, int n_in,
                              void* d_out, int out_size, void* d_ws, size_t ws_size,
                              hipStream_t stream) {
  const int* input_ids = (const int*)d_in[0];
  const int* output_ids = (const int*)d_in[1];
  const float* enc_emb = (const float*)d_in[2];
  const float* enc_Wih = (const float*)d_in[3];
  const float* enc_Whh = (const float*)d_in[4];
  const float* enc_bih = (const float*)d_in[5];
  const float* enc_bhh = (const float*)d_in[6];
  const float* dec_emb = (const float*)d_in[7];
  const float* dec_Wih = (const float*)d_in[8];
  const float* dec_Whh = (const float*)d_in[9];
  const float* dec_bih = (const float*)d_in[10];
  const float* dec_bhh = (const float*)d_in[11];
  const float* Wout = (const float*)d_in[12];
  const float* bout = (const float*)d_in[13];
  float* out = (float*)d_out;
  char* ws = (char*)d_ws;

  const size_t WL = (size_t)kG * kH;  // per-layer weight stride (elems)
  const size_t BKH = (size_t)kB * kH;

  // ---- workspace layout (bytes) ----
  size_t off = 0;
  // Region dead after encoder; Wout frags alias here (32.77 MB < 37.75 MB)
  unsigned short* wout_frag = (unsigned short*)(ws + 0);
  unsigned short* xproj_enc = (unsigned short*)(ws + off); off += (size_t)kT * kB * kG * 2;
  unsigned short* xin_enc = (unsigned short*)(ws + off); off += (size_t)kT * kB * kH * 2;
  unsigned short* wih0_enc = (unsigned short*)(ws + off); off += WL * 2;
  unsigned short* wih0_dec = (unsigned short*)(ws + off); off += WL * 2;
  // persistent regions
  unsigned short* xproj_dec = (unsigned short*)(ws + off); off += (size_t)(kT - 1) * kB * kG * 2;
  unsigned short* xin_dec = (unsigned short*)(ws + off); off += (size_t)(kT - 1) * kB * kH * 2;
  unsigned short* htop_frag = xin_dec;  // alias: xin_dec dead before decoder starts
  float* c0 = (float*)(ws + off); off += BKH * 4;
  float* c1 = (float*)(ws + off); off += BKH * 4;
  unsigned short* h0swz[2];
  unsigned short* h1swz[2];
  h0swz[0] = (unsigned short*)(ws + off); off += BKH * 2;
  h0swz[1] = (unsigned short*)(ws + off); off += BKH * 2;
  h1swz[0] = (unsigned short*)(ws + off); off += BKH * 2;
  h1swz[1] = (unsigned short*)(ws + off); off += BKH * 2;
  unsigned short* wswz[6];
  for (int i = 0; i < 6; ++i) { wswz[i] = (unsigned short*)(ws + off); off += WL * 2; }
  float* bsum_enc = (float*)(ws + off); off += kG * 4;
  float* bsum_dec = (float*)(ws + off); off += kG * 4;

  // zero c0,c1 + h frag ping-pong buffers (contiguous)
  (void)hipMemsetAsync(c0, 0, BKH * (4 + 4 + 2 + 2 + 2 + 2), stream);

  // one-time conversions + gathers (single fused launch)
  ConvJobs C = {};
  C.src[0] = enc_Whh;       C.dst[0] = wswz[0];    C.mode[0] = 0;
  C.src[1] = enc_Wih + WL;  C.dst[1] = wswz[1];    C.mode[1] = 0;
  C.src[2] = enc_Whh + WL;  C.dst[2] = wswz[2];    C.mode[2] = 0;
  C.src[3] = dec_Whh;       C.dst[3] = wswz[3];    C.mode[3] = 0;
  C.src[4] = dec_Wih + WL;  C.dst[4] = wswz[4];    C.mode[4] = 0;
  C.src[5] = dec_Whh + WL;  C.dst[5] = wswz[5];    C.mode[5] = 0;
  C.src[6] = enc_Wih;       C.dst[6] = wih0_enc;   C.mode[6] = 1;
  C.src[7] = dec_Wih;       C.dst[7] = wih0_dec;   C.mode[7] = 1;
  C.src[8] = enc_emb;       C.dst[8] = xin_enc;    C.mode[8] = 2;
  C.ids[8] = input_ids;     C.ntiles[8] = 128;
  C.src[9] = dec_emb;       C.dst[9] = xin_dec;    C.mode[9] = 2;
  C.ids[9] = output_ids;    C.ntiles[9] = 126;
  conv10<<<10 * 2048, 256, 0, stream>>>(C);
  bias_cell2<<<32, 256, 0, stream>>>(enc_bih + kG, enc_bhh + kG, bsum_enc,
                                     dec_bih + kG, dec_bhh + kG, bsum_dec);

  // layer-0 input projections, enc+dec in ONE launch (bias fused, cell-order)
  ProjArgs P;
  P.Af[0] = xin_enc;  P.Bf[0] = wih0_enc; P.b0[0] = enc_bih; P.b1[0] = enc_bhh;
  P.dst[0] = xproj_enc; P.nmt[0] = 128;
  P.Af[1] = xin_dec;  P.Bf[1] = wih0_dec; P.b0[1] = dec_bih; P.b1[1] = dec_bhh;
  P.dst[1] = xproj_dec; P.nmt[1] = 126;
  proj_mfma2<<<dim3(32, 32, 2), 256, 0, stream>>>(P);

  // ---- recurrence: launch p runs L1(p-1) and L0(p); 128 identical launches.
  // h1 state t: t < kT -> ping-pong; t >= kT -> htop_frag slot (t - kT).
  for (int p = 0; p <= 127; ++p) {
    CellJob J = {};
    J.has_l0 = (p <= 126);
    J.has_l1 = (p >= 1);
    J.A0 = h0swz[p & 1];  // H0[p-1]
    J.A1 = (p - 2 >= kT) ? (htop_frag + (size_t)(p - 2 - kT) * BKH)
                         : h1swz[(p + 1) & 1];  // H1[p-2]
    J.c0 = c0;
    J.c1 = c1;
    J.h0_out = h0swz[(p + 1) & 1];
    J.h1_out = (p - 1 >= kT) ? (htop_frag + (size_t)(p - 1 - kT) * BKH)
                             : h1swz[p & 1];
    // L0(p) operands (valid pointers even when gated off)
    if (p <= 126) {
      J.Whh0 = (p < kT) ? wswz[0] : wswz[3];
      J.xprojc = (p < kT) ? (xproj_enc + (size_t)p * kB * kG)
                          : (xproj_dec + (size_t)(p - kT) * kB * kG);
    } else {
      J.Whh0 = wswz[3];
      J.xprojc = xproj_dec;
    }
    // L1(p-1) operands
    const bool e1 = (p - 1) < kT;
    J.Wih1 = (p >= 1 && !e1) ? wswz[4] : wswz[1];
    J.Whh1 = (p >= 1 && !e1) ? wswz[5] : wswz[2];
    J.bsum1 = (p >= 1 && !e1) ? bsum_dec : bsum_enc;
    lstm_pair<<<512, 256, 0, stream>>>(J);
    if (p == 63) {
      // enc xproj fully consumed -> build Wout frags in the aliased region
      convert_frag<<<8000, 256, 0, stream>>>(Wout, wout_frag, kV * (kH / 8));
    }
  }

  // logits[:, 0, :]
  init_t0<<<(kB * kV + 255) / 256, 256, 0, stream>>>(output_ids, out);

  // logits[:, 1:, :]
  out_gemm_mfma<<<2016, 256, 0, stream>>>(htop_frag, wout_frag, bout, out);
}